// Round 9
// baseline (497.362 us; speedup 1.0000x reference)
//
#include <hip/hip_runtime.h>
#include <math.h>
#include <stdint.h>
#include <stddef.h>

#define HID 2048
#define NH 16
#define NKV 4
#define HD 128
#define GROUPS (NH / NKV)
#define BATCH 2
#define SEQ 2048

#define N_HS  8388608ull
#define N_Q   8388608ull
#define N_KV  2097152ull
#define N_WQ  4194304ull
#define N_WKV 1048576ull
#define N_WO  4194304ull

typedef __attribute__((ext_vector_type(8))) short bf16x8;
typedef __attribute__((ext_vector_type(4))) float f32x4;

#define LOG2E 1.4426950408889634f
#define CLAMP_L2 115.41560325f  // 80 * log2(e)

__device__ inline float quantv(float x, float s) {
  float q = rintf(x / s);
  return fminf(fmaxf(q, -128.0f), 127.0f);
}

__device__ inline float slot_scale(const unsigned int* slots, int i) {
  return fmaxf(__uint_as_float(slots[i]) / 127.0f, 1e-8f);
}

__device__ inline unsigned short f2bf(float x) {
  return (unsigned short)(__float_as_uint(x) >> 16);
}

__device__ inline float amax4(float4 v) {
  return fmaxf(fmaxf(fabsf(v.x), fabsf(v.y)), fmaxf(fabsf(v.z), fabsf(v.w)));
}

__device__ inline void block_amax_atomic(float m, unsigned int* slot) {
  __shared__ float red[256];
  red[threadIdx.x] = m;
  __syncthreads();
  for (int o = 128; o > 0; o >>= 1) {
    if (threadIdx.x < o) red[threadIdx.x] = fmaxf(red[threadIdx.x], red[threadIdx.x + o]);
    __syncthreads();
  }
  if (threadIdx.x == 0) atomicMax(slot, __float_as_uint(red[0]));
}

// async global -> LDS, 16B per lane (dest = wave-uniform base + lane*16)
__device__ __forceinline__ void gload_lds16(const void* g, void* l) {
  __builtin_amdgcn_global_load_lds((const __attribute__((address_space(1))) unsigned int*)g,
                                   (__attribute__((address_space(3))) unsigned int*)l, 16, 0, 0);
}

// ---------------- fused absmax over the 5 input tensors ----------------
__global__ __launch_bounds__(256) void absmax5_k(const float* __restrict__ a0,
                                                 const float* __restrict__ a1,
                                                 const float* __restrict__ a2,
                                                 const float* __restrict__ a3,
                                                 const float* __restrict__ a4,
                                                 unsigned int* __restrict__ slots) {
  const int t = blockIdx.y;
  const float* x = t == 0 ? a0 : t == 1 ? a1 : t == 2 ? a2 : t == 3 ? a3 : a4;
  const size_t n4 = (t == 0 ? N_HS : t == 1 ? N_WQ : t == 2 ? N_WKV : t == 3 ? N_WKV : N_WO) / 4;
  const float4* xp = (const float4*)x;
  float m = 0.0f;
  for (size_t i = (size_t)blockIdx.x * 256 + threadIdx.x; i < n4; i += (size_t)gridDim.x * 256)
    m = fmaxf(m, amax4(xp[i]));
  block_amax_atomic(m, slots + t);
}

// ---------------- fused quantize over 5 tensors ----------------
__global__ __launch_bounds__(256) void quant5_k(const float* __restrict__ a0,
                                                const float* __restrict__ a1,
                                                const float* __restrict__ a2,
                                                const float* __restrict__ a3,
                                                const float* __restrict__ a4,
                                                const unsigned int* __restrict__ slots,
                                                unsigned short* __restrict__ o0,
                                                unsigned short* __restrict__ o1,
                                                unsigned short* __restrict__ o2,
                                                unsigned short* __restrict__ o3,
                                                unsigned short* __restrict__ o4) {
  const int t = blockIdx.y;
  const float* x = t == 0 ? a0 : t == 1 ? a1 : t == 2 ? a2 : t == 3 ? a3 : a4;
  unsigned short* o = t == 0 ? o0 : t == 1 ? o1 : t == 2 ? o2 : t == 3 ? o3 : o4;
  const size_t n4 = (t == 0 ? N_HS : t == 1 ? N_WQ : t == 2 ? N_WKV : t == 3 ? N_WKV : N_WO) / 4;
  const float s = fmaxf(__uint_as_float(slots[t]) / 127.0f, 1e-8f);
  const float4* xp = (const float4*)x;
  ushort4* op = (ushort4*)o;
  for (size_t i = (size_t)blockIdx.x * 256 + threadIdx.x; i < n4; i += (size_t)gridDim.x * 256) {
    float4 v = xp[i];
    ushort4 r;
    r.x = f2bf(quantv(v.x, s));
    r.y = f2bf(quantv(v.y, s));
    r.z = f2bf(quantv(v.z, s));
    r.w = f2bf(quantv(v.w, s));
    op[i] = r;
  }
}

// ---------------- fused quantize q/k ----------------
__global__ __launch_bounds__(256) void quant2_k(const float* __restrict__ a0,
                                                const float* __restrict__ a1,
                                                const unsigned int* __restrict__ slots,
                                                unsigned short* __restrict__ o0,
                                                unsigned short* __restrict__ o1) {
  const int t = blockIdx.y;
  const float* x = t == 0 ? a0 : a1;
  unsigned short* o = t == 0 ? o0 : o1;
  const size_t n4 = (t == 0 ? N_Q : N_KV) / 4;
  const float s = fmaxf(__uint_as_float(slots[5 + t]) / 127.0f, 1e-8f);
  const float4* xp = (const float4*)x;
  ushort4* op = (ushort4*)o;
  for (size_t i = (size_t)blockIdx.x * 256 + threadIdx.x; i < n4; i += (size_t)gridDim.x * 256) {
    float4 v = xp[i];
    ushort4 r;
    r.x = f2bf(quantv(v.x, s));
    r.y = f2bf(quantv(v.y, s));
    r.z = f2bf(quantv(v.z, s));
    r.w = f2bf(quantv(v.w, s));
    op[i] = r;
  }
}

__global__ __launch_bounds__(256) void quant1_k(const float* __restrict__ x, size_t n4,
                                                const unsigned int* __restrict__ slot,
                                                unsigned short* __restrict__ out) {
  const float s = fmaxf(__uint_as_float(*slot) / 127.0f, 1e-8f);
  const float4* xp = (const float4*)x;
  ushort4* op = (ushort4*)out;
  for (size_t i = (size_t)blockIdx.x * 256 + threadIdx.x; i < n4; i += (size_t)gridDim.x * 256) {
    float4 v = xp[i];
    ushort4 r;
    r.x = f2bf(quantv(v.x, s));
    r.y = f2bf(quantv(v.y, s));
    r.z = f2bf(quantv(v.z, s));
    r.w = f2bf(quantv(v.w, s));
    op[i] = r;
  }
}

// ---------------- V: quantize + transpose to [b][hk][d][s] ----------------
__global__ __launch_bounds__(256) void vtq_k(const float* __restrict__ vbuf,
                                             const unsigned int* __restrict__ slots,
                                             unsigned short* __restrict__ vbt) {
  __shared__ unsigned short L[128 * 72];
  const int tid = threadIdx.x;
  const int s0 = blockIdx.x * 64;
  const int hk = blockIdx.y;
  const int b = blockIdx.z;
  const float s = fmaxf(__uint_as_float(slots[7]) / 127.0f, 1e-8f);
#pragma unroll
  for (int it = 0; it < 8; it++) {
    int idx = tid + it * 256;
    int sl = idx >> 5, c4 = idx & 31;
    float4 v = ((const float4*)(vbuf + ((size_t)(b * SEQ + s0 + sl) * NKV + hk) * HD))[c4];
    L[(c4 * 4 + 0) * 72 + sl] = f2bf(quantv(v.x, s));
    L[(c4 * 4 + 1) * 72 + sl] = f2bf(quantv(v.y, s));
    L[(c4 * 4 + 2) * 72 + sl] = f2bf(quantv(v.z, s));
    L[(c4 * 4 + 3) * 72 + sl] = f2bf(quantv(v.w, s));
  }
  __syncthreads();
  const size_t obase = ((size_t)(b * NKV + hk)) * HD * SEQ + s0;
#pragma unroll
  for (int it = 0; it < 4; it++) {
    int idx = tid + it * 256;
    int d = idx >> 3, sc = idx & 7;
    *(bf16x8*)(vbt + obase + (size_t)d * SEQ + sc * 8) = *(const bf16x8*)(&L[d * 72 + sc * 8]);
  }
}

// ---------------- MFMA GEMM body: 3-deep counted-vmcnt pipeline (T4) -------------
__device__ __forceinline__ void gemm_body(const unsigned short* __restrict__ A,
                                          const unsigned short* __restrict__ B,
                                          float* __restrict__ C, int N, int K, int m0, int n0,
                                          float sc, int amax_slot, unsigned int* slots) {
  __shared__ unsigned short As[3][128 * 32];
  __shared__ unsigned short Bs[3][128 * 32];
  const int tid = threadIdx.x;
  const int wave = tid >> 6, lane = tid & 63;
  const int l16 = lane & 15, quad = lane >> 4;
  const int wm = (wave & 1) * 64, wn = (wave >> 1) * 64;

  f32x4 acc[4][4];
#pragma unroll
  for (int i = 0; i < 4; i++)
#pragma unroll
    for (int j = 0; j < 4; j++) acc[i][j] = (f32x4){0.f, 0.f, 0.f, 0.f};

  auto STAGE = [&](int buf, int kt) {
#pragma unroll
    for (int it = 0; it < 2; it++) {
      int c = it * 256 + tid;
      int r = c >> 2, kc = (c & 3) * 8;
      gload_lds16(A + (size_t)(m0 + r) * K + kt + kc, &As[buf][(it * 256 + wave * 64) * 8]);
      gload_lds16(B + (size_t)(n0 + r) * K + kt + kc, &Bs[buf][(it * 256 + wave * 64) * 8]);
    }
  };

  const int nk = K / 32;  // K >= 96 always here
  STAGE(0, 0);
  STAGE(1, 32);
  STAGE(2, 64);
  for (int t = 0; t < nk; t++) {
    const int buf = t % 3;
    if (t + 3 < nk + 1)      asm volatile("s_waitcnt vmcnt(8)" ::: "memory");
    else if (t + 2 < nk + 1) asm volatile("s_waitcnt vmcnt(4)" ::: "memory");
    else                     asm volatile("s_waitcnt vmcnt(0)" ::: "memory");
    __builtin_amdgcn_sched_barrier(0);
    __builtin_amdgcn_s_barrier();  // buf[t] visible to all waves
    __builtin_amdgcn_sched_barrier(0);
    bf16x8 af[4], bq[4];
#pragma unroll
    for (int i = 0; i < 4; i++)
      af[i] = *(const bf16x8*)(&As[buf][(wm + i * 16 + l16) * 32 + quad * 8]);
#pragma unroll
    for (int j = 0; j < 4; j++)
      bq[j] = *(const bf16x8*)(&Bs[buf][(wn + j * 16 + l16) * 32 + quad * 8]);
    asm volatile("s_waitcnt lgkmcnt(0)" ::: "memory");
    __builtin_amdgcn_sched_barrier(0);
    __builtin_amdgcn_s_barrier();  // all waves done reading buf[t]; safe to overwrite
    __builtin_amdgcn_sched_barrier(0);
    if (t + 3 < nk) STAGE(buf, (t + 3) * 32);
#pragma unroll
    for (int i = 0; i < 4; i++)
#pragma unroll
      for (int j = 0; j < 4; j++)
        acc[i][j] = __builtin_amdgcn_mfma_f32_16x16x32_bf16(af[i], bq[j], acc[i][j], 0, 0, 0);
  }

  float am = 0.0f;
#pragma unroll
  for (int i = 0; i < 4; i++)
#pragma unroll
    for (int j = 0; j < 4; j++)
#pragma unroll
      for (int r = 0; r < 4; r++) {
        int row = m0 + wm + i * 16 + quad * 4 + r;
        int col = n0 + wn + j * 16 + l16;
        float v = acc[i][j][r] * sc;
        C[(size_t)row * N + col] = v;
        am = fmaxf(am, fabsf(v));
      }
  if (amax_slot >= 0) {
    __syncthreads();
    float* red = (float*)As;
    red[tid] = am;
    __syncthreads();
    for (int o = 128; o > 0; o >>= 1) {
      if (tid < o) red[tid] = fmaxf(red[tid], red[tid + o]);
      __syncthreads();
    }
    if (tid == 0) atomicMax(slots + amax_slot, __float_as_uint(red[0]));
  }
}

// Fused Q/K/V projection: shared A, per-block weight select.
__global__ __launch_bounds__(256) void gemm_qkv_k(const unsigned short* __restrict__ A,
                                                  const unsigned short* __restrict__ Bq,
                                                  const unsigned short* __restrict__ Bk,
                                                  const unsigned short* __restrict__ Bv,
                                                  float* __restrict__ Cq, float* __restrict__ Ck,
                                                  float* __restrict__ Cv,
                                                  unsigned int* __restrict__ slots) {
  const int nt = blockIdx.x, m0 = blockIdx.y * 128;
  const unsigned short* B;
  float* C;
  int N, n0, ib, amx;
  if (nt < 16) {
    B = Bq; C = Cq; N = 2048; n0 = nt * 128; ib = 1; amx = -1;
  } else if (nt < 20) {
    B = Bk; C = Ck; N = 512; n0 = (nt - 16) * 128; ib = 2; amx = -1;
  } else {
    B = Bv; C = Cv; N = 512; n0 = (nt - 20) * 128; ib = 3; amx = 7;
  }
  const float sc = slot_scale(slots, 0) * slot_scale(slots, ib);
  gemm_body(A, B, C, N, HID, m0, n0, sc, amx, slots);
}

__global__ __launch_bounds__(256) void gemm_o_k(const unsigned short* __restrict__ A,
                                                const unsigned short* __restrict__ B,
                                                float* __restrict__ C,
                                                unsigned int* __restrict__ slots) {
  const float sc = slot_scale(slots, 8) * slot_scale(slots, 4);
  gemm_body(A, B, C, HID, NH * HD, blockIdx.y * 128, blockIdx.x * 128, sc, -1, slots);
}

// ---------------- RoPE cos/sin table (computed once; exact libm) ----
__global__ __launch_bounds__(256) void rope_table_k(float2* __restrict__ tab) {
  int idx = blockIdx.x * 256 + threadIdx.x;  // 131072 total
  int i = idx & 63, s = idx >> 6;
  float inv = 1.0f / powf(10000.0f, (float)(2 * i) * (1.0f / 128.0f));
  float fr = (float)s * inv;
  tab[idx] = make_float2(cosf(fr), sinf(fr));
}

// ---------------- RoPE in-place + absmax ----------------
__global__ __launch_bounds__(256) void rope_kernel(float* __restrict__ t, int nh, int nhs,
                                                   const float2* __restrict__ tab,
                                                   unsigned int* __restrict__ slot) {
  const size_t total4 = (size_t)BATCH * SEQ * nh * 16;  // float4-pair items
  float am = 0.0f;
  for (size_t it = (size_t)blockIdx.x * 256 + threadIdx.x; it < total4;
       it += (size_t)gridDim.x * 256) {
    const int i4 = (int)(it & 15);
    const int h = (int)((it >> 4) & (nh - 1));
    const int s = (int)((it >> (4 + nhs)) & (SEQ - 1));
    const int b = (int)(it >> (15 + nhs));
    const size_t base = ((size_t)(b * SEQ + s) * nh + h) * HD + i4 * 4;
    float4 x1 = *(const float4*)(t + base);
    float4 x2 = *(const float4*)(t + base + 64);
    const float4* tp = (const float4*)(tab + (s << 6) + i4 * 4);
    float4 cs01 = tp[0];
    float4 cs23 = tp[1];
    float4 r1, r2;
    r1.x = x1.x * cs01.x - x2.x * cs01.y;  r2.x = x2.x * cs01.x + x1.x * cs01.y;
    r1.y = x1.y * cs01.z - x2.y * cs01.w;  r2.y = x2.y * cs01.z + x1.y * cs01.w;
    r1.z = x1.z * cs23.x - x2.z * cs23.y;  r2.z = x2.z * cs23.x + x1.z * cs23.y;
    r1.w = x1.w * cs23.z - x2.w * cs23.w;  r2.w = x2.w * cs23.z + x1.w * cs23.w;
    *(float4*)(t + base) = r1;
    *(float4*)(t + base + 64) = r2;
    am = fmaxf(am, fmaxf(amax4(r1), amax4(r2)));
  }
  block_amax_atomic(am, slot);
}

// ---------------- MFMA dual-group two-pass causal attention (swapped QK^T) ----------------
// Round-8 PMC: LDS-read-BW-bound (~90% of dur explained by K/V fragment reads). Fix: each
// block covers 128 CONTIGUOUS q-rows (group A = rows q0..q0+63, group B = +64); every K and V
// fragment ds_read feeds BOTH groups' MFMAs -> reads per unit work drop 544 -> 288 B (1.9x).
// Group A is active for all tiles except the last (contiguous, unlike round-6's far pairing).
// LDS 54272B: 3 blocks/CU (162816 <= 163840). Grid 512, balanced pairing: ids 0..255 carry
// bt 15..8, ids 256..511 carry bt 0..7 ascending -> each CU's two blocks sum to 36 tile-passes.
#define TK 64
#define KS_STRIDE (HD + 8)
#define VT_STRIDE (TK + 8)
#define PS_STRIDE (TK + 8)

__device__ __forceinline__ void ldK(bf16x8 r[4], const unsigned short* kb, int b, int hk,
                                    int j0, int tid) {
#pragma unroll
  for (int it = 0; it < 4; it++) {
    int c2 = tid + it * 256;
    int rr = c2 >> 4, c = c2 & 15;
    r[it] = *(const bf16x8*)(kb + ((size_t)(b * SEQ + j0 + rr) * NKV + hk) * HD + c * 8);
  }
}
__device__ __forceinline__ void stK(unsigned short* Ks, const bf16x8 r[4], int tid) {
#pragma unroll
  for (int it = 0; it < 4; it++) {
    int c2 = tid + it * 256;
    int rr = c2 >> 4, c = c2 & 15;
    *(bf16x8*)(&Ks[rr * KS_STRIDE + c * 8]) = r[it];
  }
}
__device__ __forceinline__ void ldV(bf16x8 r[4], const unsigned short* vbt, size_t vbase,
                                    int j0, int tid) {
#pragma unroll
  for (int it = 0; it < 4; it++) {
    int idx = tid + it * 256;
    int d = idx >> 3, sc = idx & 7;
    r[it] = *(const bf16x8*)(vbt + vbase + (size_t)d * SEQ + j0 + sc * 8);
  }
}
__device__ __forceinline__ void stV(unsigned short* Vt, const bf16x8 r[4], int tid) {
#pragma unroll
  for (int it = 0; it < 4; it++) {
    int idx = tid + it * 256;
    int d = idx >> 3, sc = idx & 7;
    *(bf16x8*)(&Vt[d * VT_STRIDE + sc * 8]) = r[it];
  }
}

// Swapped fused dual-group QK^T: one K-fragment ds_read feeds both groups' MFMAs.
// Thread holds S[key = j0 + kt*16 + quad*4 + r][q-row = wave*16 + l16 (+64 for B)].
__device__ __forceinline__ void qk4_pair(f32x4 sfrA[4], f32x4 sfrB[4], const unsigned short* Ks,
                                         const bf16x8 qfA[4], const bf16x8 qfB[4], bool doA,
                                         int l16, int quad) {
#pragma unroll
  for (int kt = 0; kt < 4; kt++) {
    f32x4 aA = {0.f, 0.f, 0.f, 0.f}, aB = {0.f, 0.f, 0.f, 0.f};
    const unsigned short* kp = &Ks[(kt * 16 + l16) * KS_STRIDE + quad * 8];
#pragma unroll
    for (int s = 0; s < 4; s++) {
      bf16x8 kf = *(const bf16x8*)(kp + s * 32);
      if (doA) aA = __builtin_amdgcn_mfma_f32_16x16x32_bf16(kf, qfA[s], aA, 0, 0, 0);
      aB = __builtin_amdgcn_mfma_f32_16x16x32_bf16(kf, qfB[s], aB, 0, 0, 0);
    }
    sfrA[kt] = aA;
    sfrB[kt] = aB;
  }
}
// l += sum of e over this tile's 16 keys (thread-local row = qrow).
__device__ __forceinline__ void lacc(float& l, const f32x4 sfr[4], float c1, bool diag,
                                     int j0, int qrow, int quad) {
  if (!diag) {
#pragma unroll
    for (int kt = 0; kt < 4; kt++)
#pragma unroll
      for (int r = 0; r < 4; r++)
        l += __builtin_amdgcn_exp2f(fminf(sfr[kt][r] * c1, CLAMP_L2));
  } else {
#pragma unroll
    for (int kt = 0; kt < 4; kt++) {
      const int key0 = j0 + kt * 16 + quad * 4;
#pragma unroll
      for (int r = 0; r < 4; r++) {
        float e = __builtin_amdgcn_exp2f(fminf(sfr[kt][r] * c1, CLAMP_L2));
        l += (key0 + r <= qrow) ? e : 0.0f;
      }
    }
  }
}
// Quantize P and write 4 consecutive keys per b64.
__device__ __forceinline__ void pquant(unsigned short* Psb, const f32x4 sfr[4],
                                       float l2il, float c1, bool diag, int j0,
                                       int qrow, int wave, int l16, int quad) {
  unsigned short* rowp = &Psb[(wave * 16 + l16) * PS_STRIDE + quad * 4];
#pragma unroll
  for (int kt = 0; kt < 4; kt++) {
    const int key0 = j0 + kt * 16 + quad * 4;
    float p0 = rintf(__builtin_amdgcn_exp2f(fminf(sfr[kt][0] * c1, CLAMP_L2) + l2il));
    float p1 = rintf(__builtin_amdgcn_exp2f(fminf(sfr[kt][1] * c1, CLAMP_L2) + l2il));
    float p2 = rintf(__builtin_amdgcn_exp2f(fminf(sfr[kt][2] * c1, CLAMP_L2) + l2il));
    float p3 = rintf(__builtin_amdgcn_exp2f(fminf(sfr[kt][3] * c1, CLAMP_L2) + l2il));
    if (diag) {
      if (key0 + 0 > qrow) p0 = 0.0f;
      if (key0 + 1 > qrow) p1 = 0.0f;
      if (key0 + 2 > qrow) p2 = 0.0f;
      if (key0 + 3 > qrow) p3 = 0.0f;
    }
    ushort4 pk;
    pk.x = f2bf(p0);
    pk.y = f2bf(p1);
    pk.z = f2bf(p2);
    pk.w = f2bf(p3);
    *(ushort4*)(rowp + kt * 16) = pk;
  }
}
// Fused dual-group PV: one V-fragment ds_read feeds both groups' MFMAs.
// Ps rows 0..63 = group A, rows 64..127 = group B; rows are wave-private (in-wave LDS order).
__device__ __forceinline__ void pvacc_pair(f32x4 ofA[8], f32x4 ofB[8], const unsigned short* Ps,
                                           const unsigned short* Vt, bool doA, int wave,
                                           int l16, int quad) {
  const unsigned short* ppA = &Ps[(wave * 16 + l16) * PS_STRIDE + quad * 8];
  const unsigned short* ppB = ppA + 64 * PS_STRIDE;
  bf16x8 pA0, pA1;
  if (doA) {
    pA0 = *(const bf16x8*)ppA;
    pA1 = *(const bf16x8*)(ppA + 32);
  }
  bf16x8 pB0 = *(const bf16x8*)ppB;
  bf16x8 pB1 = *(const bf16x8*)(ppB + 32);
#pragma unroll
  for (int n = 0; n < 8; n++) {
    const unsigned short* vp = &Vt[(n * 16 + l16) * VT_STRIDE + quad * 8];
    bf16x8 v0 = *(const bf16x8*)vp;
    bf16x8 v1 = *(const bf16x8*)(vp + 32);
    ofB[n] = __builtin_amdgcn_mfma_f32_16x16x32_bf16(pB0, v0, ofB[n], 0, 0, 0);
    ofB[n] = __builtin_amdgcn_mfma_f32_16x16x32_bf16(pB1, v1, ofB[n], 0, 0, 0);
    if (doA) {
      ofA[n] = __builtin_amdgcn_mfma_f32_16x16x32_bf16(pA0, v0, ofA[n], 0, 0, 0);
      ofA[n] = __builtin_amdgcn_mfma_f32_16x16x32_bf16(pA1, v1, ofA[n], 0, 0, 0);
    }
  }
}

__global__ __launch_bounds__(256, 3) void attn_mfma_kernel(const unsigned short* __restrict__ qb,
                                                           const unsigned short* __restrict__ kb,
                                                           const unsigned short* __restrict__ vbt,
                                                           float* __restrict__ ob,
                                                           unsigned int* __restrict__ slots) {
  __shared__ unsigned short Ks[TK * KS_STRIDE];    // 17408 B
  __shared__ unsigned short Vt[HD * VT_STRIDE];    // 18432 B
  __shared__ unsigned short Ps[128 * PS_STRIDE];   // 18432 B (A rows 0..63, B rows 64..127)

  const int tid = threadIdx.x;
  const int wave = tid >> 6;
  const int lane = tid & 63;
  const int l16 = lane & 15;
  const int quad = lane >> 4;
  // id&7 -> (b,hk) XCD grouping; id>>5 -> balanced bt pairing.
  const int id = blockIdx.x;
  const int b = (id & 7) >> 2;
  const int hk = id & 3;
  const int h = hk * GROUPS + ((id >> 3) & 3);
  const int j5 = id >> 5;                      // 0..15
  const int bt = j5 < 8 ? 15 - j5 : j5 - 8;    // CU pair sums to constant work
  const int q0 = bt * 128;
  const int nt = 2 * bt + 2;                   // tiles for group B; group A uses nt-1

  const float s_q = slot_scale(slots, 5);
  const float s_k = slot_scale(slots, 6);
  const float s_v = slot_scale(slots, 7);
  const float ss = s_q * s_k / 11.313708498984761f;  // /sqrt(128)
  const float c1 = ss * LOG2E;
  const float scale_p = 1.0f / 127.0f;
  const size_t vbase = ((size_t)(b * NKV + hk)) * HD * SEQ;

  bf16x8 qfA[4], qfB[4];
  {
    const unsigned short* qpA =
        qb + ((size_t)(b * SEQ + q0 + wave * 16 + l16) * NH + h) * HD + quad * 8;
    const unsigned short* qpB = qpA + (size_t)64 * NH * HD;
#pragma unroll
    for (int s = 0; s < 4; s++) {
      qfA[s] = *(const bf16x8*)(qpA + s * 32);
      qfB[s] = *(const bf16x8*)(qpB + s * 32);
    }
  }
  const int qrowA = q0 + wave * 16 + l16;       // swapped: thread-local q-row
  const int qrowB = qrowA + 64;
  const int qrbA = q0 + wave * 16 + quad * 4;   // epilogue rows
  const int qrbB = qrbA + 64;

  // ---- Pass A: l sums for both groups (fused K-fragment reads) ----
  float lA = 0.f, lB = 0.f;
  bf16x8 kreg[4];
  ldK(kreg, kb, b, hk, 0, tid);
  for (int t = 0; t < nt; t++) {
    const int j0 = t * TK;
    __syncthreads();
    stK(Ks, kreg, tid);
    if (t + 1 < nt) ldK(kreg, kb, b, hk, (t + 1) * TK, tid);
    __syncthreads();
    const bool doA = (t < nt - 1);
    f32x4 sfrA[4], sfrB[4];
    qk4_pair(sfrA, sfrB, Ks, qfA, qfB, doA, l16, quad);
    if (doA) lacc(lA, sfrA, c1, t == nt - 2, j0, qrowA, quad);
    lacc(lB, sfrB, c1, t == nt - 1, j0, qrowB, quad);
  }
  lA += __shfl_xor(lA, 16);
  lA += __shfl_xor(lA, 32);
  lB += __shfl_xor(lB, 16);
  lB += __shfl_xor(lB, 32);
  const float l2ilA = __log2f(127.0f / fmaxf(lA, 1e-30f));
  const float l2ilB = __log2f(127.0f / fmaxf(lB, 1e-30f));

  // ---- Pass B: recompute S, quantize P, PV for both groups (fused K/V reads) ----
  f32x4 ofA[8], ofB[8];
#pragma unroll
  for (int n = 0; n < 8; n++) {
    ofA[n] = (f32x4){0.f, 0.f, 0.f, 0.f};
    ofB[n] = (f32x4){0.f, 0.f, 0.f, 0.f};
  }
  bf16x8 vreg[4];
  ldK(kreg, kb, b, hk, 0, tid);
  ldV(vreg, vbt, vbase, 0, tid);
  for (int t = 0; t < nt; t++) {
    const int j0 = t * TK;
    __syncthreads();
    stK(Ks, kreg, tid);
    stV(Vt, vreg, tid);
    if (t + 1 < nt) {
      ldK(kreg, kb, b, hk, (t + 1) * TK, tid);
      ldV(vreg, vbt, vbase, (t + 1) * TK, tid);
    }
    __syncthreads();
    const bool doA = (t < nt - 1);
    f32x4 sfrA[4], sfrB[4];
    qk4_pair(sfrA, sfrB, Ks, qfA, qfB, doA, l16, quad);
    if (doA) pquant(Ps, sfrA, l2ilA, c1, t == nt - 2, j0, qrowA, wave, l16, quad);
    pquant(Ps + 64 * PS_STRIDE, sfrB, l2ilB, c1, t == nt - 1, j0, qrowB, wave, l16, quad);
    pvacc_pair(ofA, ofB, Ps, Vt, doA, wave, l16, quad);
  }

  // ---- epilogue ----
  const float oscale = scale_p * s_v;
  float amax = 0.0f;
#pragma unroll
  for (int n = 0; n < 8; n++)
#pragma unroll
    for (int r = 0; r < 4; r++) {
      float vA = ofA[n][r] * oscale;
      float vB = ofB[n][r] * oscale;
      ob[((size_t)(b * SEQ + qrbA + r) * NH + h) * HD + n * 16 + l16] = vA;
      ob[((size_t)(b * SEQ + qrbB + r) * NH + h) * HD + n * 16 + l16] = vB;
      amax = fmaxf(amax, fmaxf(fabsf(vA), fabsf(vB)));
    }
  // amax reduction reusing Ps as scratch (no extra LDS; keeps 3 blocks/CU)
  __syncthreads();
  float* red = (float*)Ps;
  red[tid] = amax;
  __syncthreads();
  for (int o = 128; o > 0; o >>= 1) {
    if (tid < o) red[tid] = fmaxf(red[tid], red[tid + o]);
    __syncthreads();
  }
  if (tid == 0) atomicMax(slots + 8, __float_as_uint(red[0]));
}

extern "C" void kernel_launch(void* const* d_in, const int* in_sizes, int n_in,
                              void* d_out, int out_size, void* d_ws, size_t ws_size,
                              hipStream_t stream) {
  const float* hs = (const float*)d_in[0];
  const float* wq = (const float*)d_in[3];
  const float* wk = (const float*)d_in[4];
  const float* wv = (const float*)d_in[5];
  const float* wo = (const float*)d_in[6];
  float* out = (float*)d_out;

  unsigned int* slots = (unsigned int*)d_ws;
  char* p = (char*)d_ws + 256;
  unsigned short* hsq = (unsigned short*)p;  p += 2 * N_HS;  // dead after QKV GEMM
  unsigned short* wqq = (unsigned short*)p;  p += 2 * N_WQ;
  unsigned short* wkq = (unsigned short*)p;  p += 2 * N_WKV;
  unsigned short* wvq = (unsigned short*)p;  p += 2 * N_WKV;
  unsigned short* woq = (unsigned short*)p;  p += 2 * N_WO;
  float* kbuf = (float*)p;                   p += 4 * N_KV;
  float* vbuf = (float*)p;                   p += 4 * N_KV;
  unsigned short* qbf = (unsigned short*)p;  p += 2 * N_Q;
  unsigned short* kbf = (unsigned short*)p;  p += 2 * N_KV;
  unsigned short* vbt = (unsigned short*)p;  p += 2 * N_KV;  // transposed quantized V
  float2* rtab = (float2*)p;                 // RoPE cos/sin table, 1MB
  unsigned short* aobf = hsq;  // alias: hsq dead after QKV GEMM
  float* qbuf = out;           // fp32 q-proj output lives in d_out
  float* aobuf = out;          // fp32 attn output lives in d_out

  hipMemsetAsync(d_ws, 0, 256, stream);

  // slots: 0=x 1=wq 2=wk 3=wv 4=wo 5=q 6=k 7=v 8=ao
  rope_table_k<<<(SEQ * 64) / 256, 256, 0, stream>>>(rtab);
  absmax5_k<<<dim3(256, 5), 256, 0, stream>>>(hs, wq, wk, wv, wo, slots);
  quant5_k<<<dim3(256, 5), 256, 0, stream>>>(hs, wq, wk, wv, wo, slots, hsq, wqq, wkq, wvq, woq);

  const int M = BATCH * SEQ;
  gemm_qkv_k<<<dim3(24, M / 128), 256, 0, stream>>>(hsq, wqq, wkq, wvq, qbuf, kbuf, vbuf, slots);

  rope_kernel<<<1024, 256, 0, stream>>>(qbuf, NH, 4, rtab, slots + 5);
  rope_kernel<<<256, 256, 0, stream>>>(kbuf, NKV, 2, rtab, slots + 6);

  quant2_k<<<dim3(256, 2), 256, 0, stream>>>(qbuf, kbuf, slots, qbf, kbf);
  vtq_k<<<dim3(SEQ / 64, NKV, BATCH), 256, 0, stream>>>(vbuf, slots, vbt);

  attn_mfma_kernel<<<dim3(512, 1, 1), 256, 0, stream>>>(qbf, kbf, vbt, aobuf, slots);

  quant1_k<<<256, 256, 0, stream>>>(aobuf, N_Q / 4, slots + 8, aobf);

  gemm_o_k<<<dim3(HID / 128, M / 128), 256, 0, stream>>>(aobf, woq, out, slots);
}

// Round 10
// 472.661 us; speedup vs baseline: 1.0523x; 1.0523x over previous
//
#include <hip/hip_runtime.h>
#include <math.h>
#include <stdint.h>
#include <stddef.h>

#define HID 2048
#define NH 16
#define NKV 4
#define HD 128
#define GROUPS (NH / NKV)
#define BATCH 2
#define SEQ 2048

#define N_HS  8388608ull
#define N_Q   8388608ull
#define N_KV  2097152ull
#define N_WQ  4194304ull
#define N_WKV 1048576ull
#define N_WO  4194304ull

typedef __attribute__((ext_vector_type(8))) short bf16x8;
typedef __attribute__((ext_vector_type(4))) float f32x4;

#define LOG2E 1.4426950408889634f
#define CLAMP_L2 115.41560325f  // 80 * log2(e)

__device__ inline float quantv(float x, float s) {
  float q = rintf(x / s);
  return fminf(fmaxf(q, -128.0f), 127.0f);
}

__device__ inline float slot_scale(const unsigned int* slots, int i) {
  return fmaxf(__uint_as_float(slots[i]) / 127.0f, 1e-8f);
}

__device__ inline unsigned short f2bf(float x) {
  return (unsigned short)(__float_as_uint(x) >> 16);
}

__device__ inline float amax4(float4 v) {
  return fmaxf(fmaxf(fabsf(v.x), fabsf(v.y)), fmaxf(fabsf(v.z), fabsf(v.w)));
}

__device__ inline void block_amax_atomic(float m, unsigned int* slot) {
  __shared__ float red[256];
  red[threadIdx.x] = m;
  __syncthreads();
  for (int o = 128; o > 0; o >>= 1) {
    if (threadIdx.x < o) red[threadIdx.x] = fmaxf(red[threadIdx.x], red[threadIdx.x + o]);
    __syncthreads();
  }
  if (threadIdx.x == 0) atomicMax(slot, __float_as_uint(red[0]));
}

// async global -> LDS, 16B per lane (dest = wave-uniform base + lane*16)
__device__ __forceinline__ void gload_lds16(const void* g, void* l) {
  __builtin_amdgcn_global_load_lds((const __attribute__((address_space(1))) unsigned int*)g,
                                   (__attribute__((address_space(3))) unsigned int*)l, 16, 0, 0);
}

// ---------------- fused absmax over the 5 input tensors ----------------
__global__ __launch_bounds__(256) void absmax5_k(const float* __restrict__ a0,
                                                 const float* __restrict__ a1,
                                                 const float* __restrict__ a2,
                                                 const float* __restrict__ a3,
                                                 const float* __restrict__ a4,
                                                 unsigned int* __restrict__ slots) {
  const int t = blockIdx.y;
  const float* x = t == 0 ? a0 : t == 1 ? a1 : t == 2 ? a2 : t == 3 ? a3 : a4;
  const size_t n4 = (t == 0 ? N_HS : t == 1 ? N_WQ : t == 2 ? N_WKV : t == 3 ? N_WKV : N_WO) / 4;
  const float4* xp = (const float4*)x;
  float m = 0.0f;
  for (size_t i = (size_t)blockIdx.x * 256 + threadIdx.x; i < n4; i += (size_t)gridDim.x * 256)
    m = fmaxf(m, amax4(xp[i]));
  block_amax_atomic(m, slots + t);
}

// ---------------- fused quantize over 5 tensors ----------------
__global__ __launch_bounds__(256) void quant5_k(const float* __restrict__ a0,
                                                const float* __restrict__ a1,
                                                const float* __restrict__ a2,
                                                const float* __restrict__ a3,
                                                const float* __restrict__ a4,
                                                const unsigned int* __restrict__ slots,
                                                unsigned short* __restrict__ o0,
                                                unsigned short* __restrict__ o1,
                                                unsigned short* __restrict__ o2,
                                                unsigned short* __restrict__ o3,
                                                unsigned short* __restrict__ o4) {
  const int t = blockIdx.y;
  const float* x = t == 0 ? a0 : t == 1 ? a1 : t == 2 ? a2 : t == 3 ? a3 : a4;
  unsigned short* o = t == 0 ? o0 : t == 1 ? o1 : t == 2 ? o2 : t == 3 ? o3 : o4;
  const size_t n4 = (t == 0 ? N_HS : t == 1 ? N_WQ : t == 2 ? N_WKV : t == 3 ? N_WKV : N_WO) / 4;
  const float s = fmaxf(__uint_as_float(slots[t]) / 127.0f, 1e-8f);
  const float4* xp = (const float4*)x;
  ushort4* op = (ushort4*)o;
  for (size_t i = (size_t)blockIdx.x * 256 + threadIdx.x; i < n4; i += (size_t)gridDim.x * 256) {
    float4 v = xp[i];
    ushort4 r;
    r.x = f2bf(quantv(v.x, s));
    r.y = f2bf(quantv(v.y, s));
    r.z = f2bf(quantv(v.z, s));
    r.w = f2bf(quantv(v.w, s));
    op[i] = r;
  }
}

// ---------------- fused quantize q/k ----------------
__global__ __launch_bounds__(256) void quant2_k(const float* __restrict__ a0,
                                                const float* __restrict__ a1,
                                                const unsigned int* __restrict__ slots,
                                                unsigned short* __restrict__ o0,
                                                unsigned short* __restrict__ o1) {
  const int t = blockIdx.y;
  const float* x = t == 0 ? a0 : a1;
  unsigned short* o = t == 0 ? o0 : o1;
  const size_t n4 = (t == 0 ? N_Q : N_KV) / 4;
  const float s = fmaxf(__uint_as_float(slots[5 + t]) / 127.0f, 1e-8f);
  const float4* xp = (const float4*)x;
  ushort4* op = (ushort4*)o;
  for (size_t i = (size_t)blockIdx.x * 256 + threadIdx.x; i < n4; i += (size_t)gridDim.x * 256) {
    float4 v = xp[i];
    ushort4 r;
    r.x = f2bf(quantv(v.x, s));
    r.y = f2bf(quantv(v.y, s));
    r.z = f2bf(quantv(v.z, s));
    r.w = f2bf(quantv(v.w, s));
    op[i] = r;
  }
}

__global__ __launch_bounds__(256) void quant1_k(const float* __restrict__ x, size_t n4,
                                                const unsigned int* __restrict__ slot,
                                                unsigned short* __restrict__ out) {
  const float s = fmaxf(__uint_as_float(*slot) / 127.0f, 1e-8f);
  const float4* xp = (const float4*)x;
  ushort4* op = (ushort4*)out;
  for (size_t i = (size_t)blockIdx.x * 256 + threadIdx.x; i < n4; i += (size_t)gridDim.x * 256) {
    float4 v = xp[i];
    ushort4 r;
    r.x = f2bf(quantv(v.x, s));
    r.y = f2bf(quantv(v.y, s));
    r.z = f2bf(quantv(v.z, s));
    r.w = f2bf(quantv(v.w, s));
    op[i] = r;
  }
}

// ---------------- V: quantize + transpose to [b][hk][d][s] ----------------
__global__ __launch_bounds__(256) void vtq_k(const float* __restrict__ vbuf,
                                             const unsigned int* __restrict__ slots,
                                             unsigned short* __restrict__ vbt) {
  __shared__ unsigned short L[128 * 72];
  const int tid = threadIdx.x;
  const int s0 = blockIdx.x * 64;
  const int hk = blockIdx.y;
  const int b = blockIdx.z;
  const float s = fmaxf(__uint_as_float(slots[7]) / 127.0f, 1e-8f);
#pragma unroll
  for (int it = 0; it < 8; it++) {
    int idx = tid + it * 256;
    int sl = idx >> 5, c4 = idx & 31;
    float4 v = ((const float4*)(vbuf + ((size_t)(b * SEQ + s0 + sl) * NKV + hk) * HD))[c4];
    L[(c4 * 4 + 0) * 72 + sl] = f2bf(quantv(v.x, s));
    L[(c4 * 4 + 1) * 72 + sl] = f2bf(quantv(v.y, s));
    L[(c4 * 4 + 2) * 72 + sl] = f2bf(quantv(v.z, s));
    L[(c4 * 4 + 3) * 72 + sl] = f2bf(quantv(v.w, s));
  }
  __syncthreads();
  const size_t obase = ((size_t)(b * NKV + hk)) * HD * SEQ + s0;
#pragma unroll
  for (int it = 0; it < 4; it++) {
    int idx = tid + it * 256;
    int d = idx >> 3, sc = idx & 7;
    *(bf16x8*)(vbt + obase + (size_t)d * SEQ + sc * 8) = *(const bf16x8*)(&L[d * 72 + sc * 8]);
  }
}

// ---------------- MFMA GEMM body: 3-deep counted-vmcnt pipeline (T4) -------------
__device__ __forceinline__ void gemm_body(const unsigned short* __restrict__ A,
                                          const unsigned short* __restrict__ B,
                                          float* __restrict__ C, int N, int K, int m0, int n0,
                                          float sc, int amax_slot, unsigned int* slots) {
  __shared__ unsigned short As[3][128 * 32];
  __shared__ unsigned short Bs[3][128 * 32];
  const int tid = threadIdx.x;
  const int wave = tid >> 6, lane = tid & 63;
  const int l16 = lane & 15, quad = lane >> 4;
  const int wm = (wave & 1) * 64, wn = (wave >> 1) * 64;

  f32x4 acc[4][4];
#pragma unroll
  for (int i = 0; i < 4; i++)
#pragma unroll
    for (int j = 0; j < 4; j++) acc[i][j] = (f32x4){0.f, 0.f, 0.f, 0.f};

  auto STAGE = [&](int buf, int kt) {
#pragma unroll
    for (int it = 0; it < 2; it++) {
      int c = it * 256 + tid;
      int r = c >> 2, kc = (c & 3) * 8;
      gload_lds16(A + (size_t)(m0 + r) * K + kt + kc, &As[buf][(it * 256 + wave * 64) * 8]);
      gload_lds16(B + (size_t)(n0 + r) * K + kt + kc, &Bs[buf][(it * 256 + wave * 64) * 8]);
    }
  };

  const int nk = K / 32;  // K >= 96 always here
  STAGE(0, 0);
  STAGE(1, 32);
  STAGE(2, 64);
  for (int t = 0; t < nk; t++) {
    const int buf = t % 3;
    if (t + 3 < nk + 1)      asm volatile("s_waitcnt vmcnt(8)" ::: "memory");
    else if (t + 2 < nk + 1) asm volatile("s_waitcnt vmcnt(4)" ::: "memory");
    else                     asm volatile("s_waitcnt vmcnt(0)" ::: "memory");
    __builtin_amdgcn_sched_barrier(0);
    __builtin_amdgcn_s_barrier();  // buf[t] visible to all waves
    __builtin_amdgcn_sched_barrier(0);
    bf16x8 af[4], bq[4];
#pragma unroll
    for (int i = 0; i < 4; i++)
      af[i] = *(const bf16x8*)(&As[buf][(wm + i * 16 + l16) * 32 + quad * 8]);
#pragma unroll
    for (int j = 0; j < 4; j++)
      bq[j] = *(const bf16x8*)(&Bs[buf][(wn + j * 16 + l16) * 32 + quad * 8]);
    asm volatile("s_waitcnt lgkmcnt(0)" ::: "memory");
    __builtin_amdgcn_sched_barrier(0);
    __builtin_amdgcn_s_barrier();  // all waves done reading buf[t]; safe to overwrite
    __builtin_amdgcn_sched_barrier(0);
    if (t + 3 < nk) STAGE(buf, (t + 3) * 32);
#pragma unroll
    for (int i = 0; i < 4; i++)
#pragma unroll
      for (int j = 0; j < 4; j++)
        acc[i][j] = __builtin_amdgcn_mfma_f32_16x16x32_bf16(af[i], bq[j], acc[i][j], 0, 0, 0);
  }

  float am = 0.0f;
#pragma unroll
  for (int i = 0; i < 4; i++)
#pragma unroll
    for (int j = 0; j < 4; j++)
#pragma unroll
      for (int r = 0; r < 4; r++) {
        int row = m0 + wm + i * 16 + quad * 4 + r;
        int col = n0 + wn + j * 16 + l16;
        float v = acc[i][j][r] * sc;
        C[(size_t)row * N + col] = v;
        am = fmaxf(am, fabsf(v));
      }
  if (amax_slot >= 0) {
    __syncthreads();
    float* red = (float*)As;
    red[tid] = am;
    __syncthreads();
    for (int o = 128; o > 0; o >>= 1) {
      if (tid < o) red[tid] = fmaxf(red[tid], red[tid + o]);
      __syncthreads();
    }
    if (tid == 0) atomicMax(slots + amax_slot, __float_as_uint(red[0]));
  }
}

// Fused Q/K/V projection: shared A, per-block weight select.
__global__ __launch_bounds__(256) void gemm_qkv_k(const unsigned short* __restrict__ A,
                                                  const unsigned short* __restrict__ Bq,
                                                  const unsigned short* __restrict__ Bk,
                                                  const unsigned short* __restrict__ Bv,
                                                  float* __restrict__ Cq, float* __restrict__ Ck,
                                                  float* __restrict__ Cv,
                                                  unsigned int* __restrict__ slots) {
  const int nt = blockIdx.x, m0 = blockIdx.y * 128;
  const unsigned short* B;
  float* C;
  int N, n0, ib, amx;
  if (nt < 16) {
    B = Bq; C = Cq; N = 2048; n0 = nt * 128; ib = 1; amx = -1;
  } else if (nt < 20) {
    B = Bk; C = Ck; N = 512; n0 = (nt - 16) * 128; ib = 2; amx = -1;
  } else {
    B = Bv; C = Cv; N = 512; n0 = (nt - 20) * 128; ib = 3; amx = 7;
  }
  const float sc = slot_scale(slots, 0) * slot_scale(slots, ib);
  gemm_body(A, B, C, N, HID, m0, n0, sc, amx, slots);
}

__global__ __launch_bounds__(256) void gemm_o_k(const unsigned short* __restrict__ A,
                                                const unsigned short* __restrict__ B,
                                                float* __restrict__ C,
                                                unsigned int* __restrict__ slots) {
  const float sc = slot_scale(slots, 8) * slot_scale(slots, 4);
  gemm_body(A, B, C, HID, NH * HD, blockIdx.y * 128, blockIdx.x * 128, sc, -1, slots);
}

// ---------------- RoPE cos/sin table (computed once; exact libm) ----
__global__ __launch_bounds__(256) void rope_table_k(float2* __restrict__ tab) {
  int idx = blockIdx.x * 256 + threadIdx.x;  // 131072 total
  int i = idx & 63, s = idx >> 6;
  float inv = 1.0f / powf(10000.0f, (float)(2 * i) * (1.0f / 128.0f));
  float fr = (float)s * inv;
  tab[idx] = make_float2(cosf(fr), sinf(fr));
}

// ---------------- RoPE in-place + absmax ----------------
__global__ __launch_bounds__(256) void rope_kernel(float* __restrict__ t, int nh, int nhs,
                                                   const float2* __restrict__ tab,
                                                   unsigned int* __restrict__ slot) {
  const size_t total4 = (size_t)BATCH * SEQ * nh * 16;  // float4-pair items
  float am = 0.0f;
  for (size_t it = (size_t)blockIdx.x * 256 + threadIdx.x; it < total4;
       it += (size_t)gridDim.x * 256) {
    const int i4 = (int)(it & 15);
    const int h = (int)((it >> 4) & (nh - 1));
    const int s = (int)((it >> (4 + nhs)) & (SEQ - 1));
    const int b = (int)(it >> (15 + nhs));
    const size_t base = ((size_t)(b * SEQ + s) * nh + h) * HD + i4 * 4;
    float4 x1 = *(const float4*)(t + base);
    float4 x2 = *(const float4*)(t + base + 64);
    const float4* tp = (const float4*)(tab + (s << 6) + i4 * 4);
    float4 cs01 = tp[0];
    float4 cs23 = tp[1];
    float4 r1, r2;
    r1.x = x1.x * cs01.x - x2.x * cs01.y;  r2.x = x2.x * cs01.x + x1.x * cs01.y;
    r1.y = x1.y * cs01.z - x2.y * cs01.w;  r2.y = x2.y * cs01.z + x1.y * cs01.w;
    r1.z = x1.z * cs23.x - x2.z * cs23.y;  r2.z = x2.z * cs23.x + x1.z * cs23.y;
    r1.w = x1.w * cs23.z - x2.w * cs23.w;  r2.w = x2.w * cs23.z + x1.w * cs23.w;
    *(float4*)(t + base) = r1;
    *(float4*)(t + base + 64) = r2;
    am = fmaxf(am, fmaxf(amax4(r1), amax4(r2)));
  }
  block_amax_atomic(am, slot);
}

// ---------------- MFMA single-tile two-pass causal attention (key-sliced QK^T) ------------
// Round-8 structure (1024 blocks, 64 q-rows/block, descending tiles) was LDS-read-BW-bound:
// all 4 waves read IDENTICAL K fragments (4x redundant LDS traffic). Round-9's dual-group fix
// destroyed parallelism (512 blocks, 1.8x longer critical path) and regressed. This version
// keeps the round-8 grid and instead re-slices QK^T: wave w owns key-slice [w*16,w*16+16) and
// computes ALL 4 q-rowgroups (Q for 64 rows held in registers, loop-invariant, +48 VGPR).
// K-reads: 256 -> 64 B/thread/tile in both passes (total 800 -> 416 B, 1.9x). MFMA count
// unchanged. Cost: one cross-wave l-reduce (once) + one extra barrier per pass-B tile.
#define TK 64
#define KS_STRIDE (HD + 8)
#define VT_STRIDE (TK + 8)
#define PS_STRIDE (TK + 8)

__device__ __forceinline__ void ldK(bf16x8 r[4], const unsigned short* kb, int b, int hk,
                                    int j0, int tid) {
#pragma unroll
  for (int it = 0; it < 4; it++) {
    int c2 = tid + it * 256;
    int rr = c2 >> 4, c = c2 & 15;
    r[it] = *(const bf16x8*)(kb + ((size_t)(b * SEQ + j0 + rr) * NKV + hk) * HD + c * 8);
  }
}
__device__ __forceinline__ void stK(unsigned short* Ks, const bf16x8 r[4], int tid) {
#pragma unroll
  for (int it = 0; it < 4; it++) {
    int c2 = tid + it * 256;
    int rr = c2 >> 4, c = c2 & 15;
    *(bf16x8*)(&Ks[rr * KS_STRIDE + c * 8]) = r[it];
  }
}
__device__ __forceinline__ void ldV(bf16x8 r[4], const unsigned short* vbt, size_t vbase,
                                    int j0, int tid) {
#pragma unroll
  for (int it = 0; it < 4; it++) {
    int idx = tid + it * 256;
    int d = idx >> 3, sc = idx & 7;
    r[it] = *(const bf16x8*)(vbt + vbase + (size_t)d * SEQ + j0 + sc * 8);
  }
}
__device__ __forceinline__ void stV(unsigned short* Vt, const bf16x8 r[4], int tid) {
#pragma unroll
  for (int it = 0; it < 4; it++) {
    int idx = tid + it * 256;
    int d = idx >> 3, sc = idx & 7;
    *(bf16x8*)(&Vt[d * VT_STRIDE + sc * 8]) = r[it];
  }
}

// Load this wave's 16-key slice of the staged K tile (read ONCE, reused for all 4 rowgroups).
__device__ __forceinline__ void ldKf(bf16x8 kf[4], const unsigned short* Ks, int wave,
                                     int l16, int quad) {
  const unsigned short* kp = &Ks[(wave * 16 + l16) * KS_STRIDE + quad * 8];
#pragma unroll
  for (int s = 0; s < 4; s++) kf[s] = *(const bf16x8*)(kp + s * 32);
}
// One rowgroup's QK^T: S[key = wave*16 + quad*4 + r][qrow = g*16 + l16].
__device__ __forceinline__ f32x4 qk_g(const bf16x8 kf[4], const bf16x8* qfg) {
  f32x4 a = {0.f, 0.f, 0.f, 0.f};
#pragma unroll
  for (int s = 0; s < 4; s++)
    a = __builtin_amdgcn_mfma_f32_16x16x32_bf16(kf[s], qfg[s], a, 0, 0, 0);
  return a;
}
// PV: wave reads its own q-rows' P (written cross-wave; barrier before this).
__device__ __forceinline__ void pvacc1(f32x4 of[8], const unsigned short* Ps,
                                       const unsigned short* Vt, int wave, int l16, int quad) {
  const unsigned short* pp = &Ps[(wave * 16 + l16) * PS_STRIDE + quad * 8];
  bf16x8 p0 = *(const bf16x8*)pp;
  bf16x8 p1 = *(const bf16x8*)(pp + 32);
#pragma unroll
  for (int n = 0; n < 8; n++) {
    const unsigned short* vp = &Vt[(n * 16 + l16) * VT_STRIDE + quad * 8];
    of[n] = __builtin_amdgcn_mfma_f32_16x16x32_bf16(p0, *(const bf16x8*)vp, of[n], 0, 0, 0);
    of[n] = __builtin_amdgcn_mfma_f32_16x16x32_bf16(p1, *(const bf16x8*)(vp + 32), of[n],
                                                    0, 0, 0);
  }
}

__global__ __launch_bounds__(256, 3) void attn_mfma_kernel(const unsigned short* __restrict__ qb,
                                                           const unsigned short* __restrict__ kb,
                                                           const unsigned short* __restrict__ vbt,
                                                           float* __restrict__ ob,
                                                           unsigned int* __restrict__ slots) {
  __shared__ unsigned short Ks[TK * KS_STRIDE];   // 17408 B
  __shared__ unsigned short Vt[HD * VT_STRIDE];   // 18432 B
  __shared__ unsigned short Ps[64 * PS_STRIDE];   //  9216 B  (total 45056 -> 3 blocks/CU)

  const int tid = threadIdx.x;
  const int wave = tid >> 6;
  const int lane = tid & 63;
  const int l16 = lane & 15;
  const int quad = lane >> 4;
  // XCD swizzle: id&7 -> (b,hk); big causal tiles dispatch first.
  const int id = blockIdx.x;
  const int b = (id & 7) >> 2;
  const int hk = id & 3;
  const int j = id >> 3;               // 0..127
  const int h = hk * GROUPS + (j & 3);
  const int tile = 31 - (j >> 2);      // 31..0
  const int q0 = tile * 64, nt = tile + 1;

  const float s_q = slot_scale(slots, 5);
  const float s_k = slot_scale(slots, 6);
  const float s_v = slot_scale(slots, 7);
  const float ss = s_q * s_k / 11.313708498984761f;  // /sqrt(128)
  const float c1 = ss * LOG2E;
  const float scale_p = 1.0f / 127.0f;
  const size_t vbase = ((size_t)(b * NKV + hk)) * HD * SEQ;

  // Q for ALL 64 rows of this block's tile: qf[g*4+s], g = rowgroup, s = K-dim chunk.
  bf16x8 qf[16];
#pragma unroll
  for (int g = 0; g < 4; g++) {
    const unsigned short* qp =
        qb + ((size_t)(b * SEQ + q0 + g * 16 + l16) * NH + h) * HD + quad * 8;
#pragma unroll
    for (int s = 0; s < 4; s++) qf[g * 4 + s] = *(const bf16x8*)(qp + s * 32);
  }
  const int qrb = q0 + wave * 16 + quad * 4;  // epilogue rows (PV output, unchanged)

  // ---- Pass A: l sums (key-sliced; thread accumulates 4 rowgroups) ----
  float l[4] = {0.f, 0.f, 0.f, 0.f};
  bf16x8 kreg[4];
  ldK(kreg, kb, b, hk, 0, tid);
  for (int t = 0; t < nt; t++) {
    __syncthreads();
    stK(Ks, kreg, tid);
    if (t + 1 < nt) ldK(kreg, kb, b, hk, (t + 1) * TK, tid);
    __syncthreads();
    bf16x8 kf[4];
    ldKf(kf, Ks, wave, l16, quad);
    const bool diag = (t == nt - 1);
    const int key0 = t * TK + wave * 16 + quad * 4;
#pragma unroll
    for (int g = 0; g < 4; g++) {
      f32x4 a = qk_g(kf, &qf[g * 4]);
      if (!diag) {
#pragma unroll
        for (int r = 0; r < 4; r++)
          l[g] += __builtin_amdgcn_exp2f(fminf(a[r] * c1, CLAMP_L2));
      } else {
        const int qrow = q0 + g * 16 + l16;
#pragma unroll
        for (int r = 0; r < 4; r++) {
          float e = __builtin_amdgcn_exp2f(fminf(a[r] * c1, CLAMP_L2));
          l[g] += (key0 + r <= qrow) ? e : 0.0f;
        }
      }
    }
  }
  // reduce: quads (same wave, same qrow, different keys) then across waves (different slices)
#pragma unroll
  for (int g = 0; g < 4; g++) {
    l[g] += __shfl_xor(l[g], 16);
    l[g] += __shfl_xor(l[g], 32);
  }
  {
    float* Lr = (float*)Ps;  // 4 waves x 4 g x 16 rows = 1KB scratch
    if (quad == 0) {
#pragma unroll
      for (int g = 0; g < 4; g++) Lr[wave * 64 + g * 16 + l16] = l[g];
    }
    __syncthreads();
#pragma unroll
    for (int g = 0; g < 4; g++) {
      float s = Lr[g * 16 + l16] + Lr[64 + g * 16 + l16] + Lr[128 + g * 16 + l16] +
                Lr[192 + g * 16 + l16];
      l[g] = __log2f(127.0f / fmaxf(s, 1e-30f));  // reuse l[] as l2il[]
    }
  }

  // ---- Pass B: recompute S (key-sliced), quantize P, PV ----
  f32x4 of[8];
#pragma unroll
  for (int n = 0; n < 8; n++) of[n] = (f32x4){0.f, 0.f, 0.f, 0.f};
  bf16x8 vreg[4];
  ldK(kreg, kb, b, hk, 0, tid);
  ldV(vreg, vbt, vbase, 0, tid);
  for (int t = 0; t < nt; t++) {
    __syncthreads();  // also guarantees Lr reads / prev pvacc done before Ps overwrite
    stK(Ks, kreg, tid);
    stV(Vt, vreg, tid);
    if (t + 1 < nt) {
      ldK(kreg, kb, b, hk, (t + 1) * TK, tid);
      ldV(vreg, vbt, vbase, (t + 1) * TK, tid);
    }
    __syncthreads();
    bf16x8 kf[4];
    ldKf(kf, Ks, wave, l16, quad);
    const bool diag = (t == nt - 1);
    const int key0 = t * TK + wave * 16 + quad * 4;
#pragma unroll
    for (int g = 0; g < 4; g++) {
      f32x4 a = qk_g(kf, &qf[g * 4]);
      float p0 = rintf(__builtin_amdgcn_exp2f(fminf(a[0] * c1, CLAMP_L2) + l[g]));
      float p1 = rintf(__builtin_amdgcn_exp2f(fminf(a[1] * c1, CLAMP_L2) + l[g]));
      float p2 = rintf(__builtin_amdgcn_exp2f(fminf(a[2] * c1, CLAMP_L2) + l[g]));
      float p3 = rintf(__builtin_amdgcn_exp2f(fminf(a[3] * c1, CLAMP_L2) + l[g]));
      if (diag) {
        const int qrow = q0 + g * 16 + l16;
        if (key0 + 0 > qrow) p0 = 0.0f;
        if (key0 + 1 > qrow) p1 = 0.0f;
        if (key0 + 2 > qrow) p2 = 0.0f;
        if (key0 + 3 > qrow) p3 = 0.0f;
      }
      ushort4 pk;
      pk.x = f2bf(p0);
      pk.y = f2bf(p1);
      pk.z = f2bf(p2);
      pk.w = f2bf(p3);
      *(ushort4*)(&Ps[(g * 16 + l16) * PS_STRIDE + wave * 16 + quad * 4]) = pk;
    }
    __syncthreads();  // P written cross-wave; make visible before PV
    pvacc1(of, Ps, Vt, wave, l16, quad);
  }

  // ---- epilogue ----
  const float oscale = scale_p * s_v;
  float amax = 0.0f;
#pragma unroll
  for (int n = 0; n < 8; n++)
#pragma unroll
    for (int r = 0; r < 4; r++) {
      float v = of[n][r] * oscale;
      ob[((size_t)(b * SEQ + qrb + r) * NH + h) * HD + n * 16 + l16] = v;
      amax = fmaxf(amax, fabsf(v));
    }
  // amax reduction reusing Ps as scratch (keeps LDS at 45KB for 3 blocks/CU)
  __syncthreads();
  float* red = (float*)Ps;
  red[tid] = amax;
  __syncthreads();
  for (int o = 128; o > 0; o >>= 1) {
    if (tid < o) red[tid] = fmaxf(red[tid], red[tid + o]);
    __syncthreads();
  }
  if (tid == 0) atomicMax(slots + 8, __float_as_uint(red[0]));
}

extern "C" void kernel_launch(void* const* d_in, const int* in_sizes, int n_in,
                              void* d_out, int out_size, void* d_ws, size_t ws_size,
                              hipStream_t stream) {
  const float* hs = (const float*)d_in[0];
  const float* wq = (const float*)d_in[3];
  const float* wk = (const float*)d_in[4];
  const float* wv = (const float*)d_in[5];
  const float* wo = (const float*)d_in[6];
  float* out = (float*)d_out;

  unsigned int* slots = (unsigned int*)d_ws;
  char* p = (char*)d_ws + 256;
  unsigned short* hsq = (unsigned short*)p;  p += 2 * N_HS;  // dead after QKV GEMM
  unsigned short* wqq = (unsigned short*)p;  p += 2 * N_WQ;
  unsigned short* wkq = (unsigned short*)p;  p += 2 * N_WKV;
  unsigned short* wvq = (unsigned short*)p;  p += 2 * N_WKV;
  unsigned short* woq = (unsigned short*)p;  p += 2 * N_WO;
  float* kbuf = (float*)p;                   p += 4 * N_KV;
  float* vbuf = (float*)p;                   p += 4 * N_KV;
  unsigned short* qbf = (unsigned short*)p;  p += 2 * N_Q;
  unsigned short* kbf = (unsigned short*)p;  p += 2 * N_KV;
  unsigned short* vbt = (unsigned short*)p;  p += 2 * N_KV;  // transposed quantized V
  float2* rtab = (float2*)p;                 // RoPE cos/sin table, 1MB
  unsigned short* aobf = hsq;  // alias: hsq dead after QKV GEMM
  float* qbuf = out;           // fp32 q-proj output lives in d_out
  float* aobuf = out;          // fp32 attn output lives in d_out

  hipMemsetAsync(d_ws, 0, 256, stream);

  // slots: 0=x 1=wq 2=wk 3=wv 4=wo 5=q 6=k 7=v 8=ao
  rope_table_k<<<(SEQ * 64) / 256, 256, 0, stream>>>(rtab);
  absmax5_k<<<dim3(256, 5), 256, 0, stream>>>(hs, wq, wk, wv, wo, slots);
  quant5_k<<<dim3(256, 5), 256, 0, stream>>>(hs, wq, wk, wv, wo, slots, hsq, wqq, wkq, wvq, woq);

  const int M = BATCH * SEQ;
  gemm_qkv_k<<<dim3(24, M / 128), 256, 0, stream>>>(hsq, wqq, wkq, wvq, qbuf, kbuf, vbuf, slots);

  rope_kernel<<<1024, 256, 0, stream>>>(qbuf, NH, 4, rtab, slots + 5);
  rope_kernel<<<256, 256, 0, stream>>>(kbuf, NKV, 2, rtab, slots + 6);

  quant2_k<<<dim3(256, 2), 256, 0, stream>>>(qbuf, kbuf, slots, qbf, kbf);
  vtq_k<<<dim3(SEQ / 64, NKV, BATCH), 256, 0, stream>>>(vbuf, slots, vbt);

  attn_mfma_kernel<<<dim3(1024, 1, 1), 256, 0, stream>>>(qbf, kbf, vbt, aobuf, slots);

  quant1_k<<<256, 256, 0, stream>>>(aobuf, N_Q / 4, slots + 8, aobf);

  gemm_o_k<<<dim3(HID / 128, M / 128), 256, 0, stream>>>(aobf, woq, out, slots);
}

// Round 11
// 416.546 us; speedup vs baseline: 1.1940x; 1.1347x over previous
//
#include <hip/hip_runtime.h>
#include <math.h>
#include <stdint.h>
#include <stddef.h>

#define HID 2048
#define NH 16
#define NKV 4
#define HD 128
#define GROUPS (NH / NKV)
#define BATCH 2
#define SEQ 2048

#define N_HS  8388608ull
#define N_Q   8388608ull
#define N_KV  2097152ull
#define N_WQ  4194304ull
#define N_WKV 1048576ull
#define N_WO  4194304ull

typedef __attribute__((ext_vector_type(8))) short bf16x8;
typedef __attribute__((ext_vector_type(4))) float f32x4;

#define LOG2E 1.4426950408889634f
#define CLAMP_L2 115.41560325f  // 80 * log2(e)

__device__ inline float quantv(float x, float s) {
  float q = rintf(x / s);
  return fminf(fmaxf(q, -128.0f), 127.0f);
}

__device__ inline float slot_scale(const unsigned int* slots, int i) {
  return fmaxf(__uint_as_float(slots[i]) / 127.0f, 1e-8f);
}

__device__ inline unsigned short f2bf(float x) {
  return (unsigned short)(__float_as_uint(x) >> 16);
}

__device__ inline float amax4(float4 v) {
  return fmaxf(fmaxf(fabsf(v.x), fabsf(v.y)), fmaxf(fabsf(v.z), fabsf(v.w)));
}

__device__ inline void block_amax_atomic(float m, unsigned int* slot) {
  __shared__ float red[256];
  red[threadIdx.x] = m;
  __syncthreads();
  for (int o = 128; o > 0; o >>= 1) {
    if (threadIdx.x < o) red[threadIdx.x] = fmaxf(red[threadIdx.x], red[threadIdx.x + o]);
    __syncthreads();
  }
  if (threadIdx.x == 0) atomicMax(slot, __float_as_uint(red[0]));
}

// async global -> LDS, 16B per lane (dest = wave-uniform base + lane*16)
__device__ __forceinline__ void gload_lds16(const void* g, void* l) {
  __builtin_amdgcn_global_load_lds((const __attribute__((address_space(1))) unsigned int*)g,
                                   (__attribute__((address_space(3))) unsigned int*)l, 16, 0, 0);
}

// ---------------- fused absmax over the 5 input tensors ----------------
__global__ __launch_bounds__(256) void absmax5_k(const float* __restrict__ a0,
                                                 const float* __restrict__ a1,
                                                 const float* __restrict__ a2,
                                                 const float* __restrict__ a3,
                                                 const float* __restrict__ a4,
                                                 unsigned int* __restrict__ slots) {
  const int t = blockIdx.y;
  const float* x = t == 0 ? a0 : t == 1 ? a1 : t == 2 ? a2 : t == 3 ? a3 : a4;
  const size_t n4 = (t == 0 ? N_HS : t == 1 ? N_WQ : t == 2 ? N_WKV : t == 3 ? N_WKV : N_WO) / 4;
  const float4* xp = (const float4*)x;
  float m = 0.0f;
  for (size_t i = (size_t)blockIdx.x * 256 + threadIdx.x; i < n4; i += (size_t)gridDim.x * 256)
    m = fmaxf(m, amax4(xp[i]));
  block_amax_atomic(m, slots + t);
}

// ---------------- fused quantize over 5 tensors ----------------
__global__ __launch_bounds__(256) void quant5_k(const float* __restrict__ a0,
                                                const float* __restrict__ a1,
                                                const float* __restrict__ a2,
                                                const float* __restrict__ a3,
                                                const float* __restrict__ a4,
                                                const unsigned int* __restrict__ slots,
                                                unsigned short* __restrict__ o0,
                                                unsigned short* __restrict__ o1,
                                                unsigned short* __restrict__ o2,
                                                unsigned short* __restrict__ o3,
                                                unsigned short* __restrict__ o4) {
  const int t = blockIdx.y;
  const float* x = t == 0 ? a0 : t == 1 ? a1 : t == 2 ? a2 : t == 3 ? a3 : a4;
  unsigned short* o = t == 0 ? o0 : t == 1 ? o1 : t == 2 ? o2 : t == 3 ? o3 : o4;
  const size_t n4 = (t == 0 ? N_HS : t == 1 ? N_WQ : t == 2 ? N_WKV : t == 3 ? N_WKV : N_WO) / 4;
  const float s = fmaxf(__uint_as_float(slots[t]) / 127.0f, 1e-8f);
  const float4* xp = (const float4*)x;
  ushort4* op = (ushort4*)o;
  for (size_t i = (size_t)blockIdx.x * 256 + threadIdx.x; i < n4; i += (size_t)gridDim.x * 256) {
    float4 v = xp[i];
    ushort4 r;
    r.x = f2bf(quantv(v.x, s));
    r.y = f2bf(quantv(v.y, s));
    r.z = f2bf(quantv(v.z, s));
    r.w = f2bf(quantv(v.w, s));
    op[i] = r;
  }
}

// ---------------- fused quantize q/k ----------------
__global__ __launch_bounds__(256) void quant2_k(const float* __restrict__ a0,
                                                const float* __restrict__ a1,
                                                const unsigned int* __restrict__ slots,
                                                unsigned short* __restrict__ o0,
                                                unsigned short* __restrict__ o1) {
  const int t = blockIdx.y;
  const float* x = t == 0 ? a0 : a1;
  unsigned short* o = t == 0 ? o0 : o1;
  const size_t n4 = (t == 0 ? N_Q : N_KV) / 4;
  const float s = fmaxf(__uint_as_float(slots[5 + t]) / 127.0f, 1e-8f);
  const float4* xp = (const float4*)x;
  ushort4* op = (ushort4*)o;
  for (size_t i = (size_t)blockIdx.x * 256 + threadIdx.x; i < n4; i += (size_t)gridDim.x * 256) {
    float4 v = xp[i];
    ushort4 r;
    r.x = f2bf(quantv(v.x, s));
    r.y = f2bf(quantv(v.y, s));
    r.z = f2bf(quantv(v.z, s));
    r.w = f2bf(quantv(v.w, s));
    op[i] = r;
  }
}

__global__ __launch_bounds__(256) void quant1_k(const float* __restrict__ x, size_t n4,
                                                const unsigned int* __restrict__ slot,
                                                unsigned short* __restrict__ out) {
  const float s = fmaxf(__uint_as_float(*slot) / 127.0f, 1e-8f);
  const float4* xp = (const float4*)x;
  ushort4* op = (ushort4*)out;
  for (size_t i = (size_t)blockIdx.x * 256 + threadIdx.x; i < n4; i += (size_t)gridDim.x * 256) {
    float4 v = xp[i];
    ushort4 r;
    r.x = f2bf(quantv(v.x, s));
    r.y = f2bf(quantv(v.y, s));
    r.z = f2bf(quantv(v.z, s));
    r.w = f2bf(quantv(v.w, s));
    op[i] = r;
  }
}

// ---------------- V: quantize + transpose to [b][hk][d][s] ----------------
__global__ __launch_bounds__(256) void vtq_k(const float* __restrict__ vbuf,
                                             const unsigned int* __restrict__ slots,
                                             unsigned short* __restrict__ vbt) {
  __shared__ unsigned short L[128 * 72];
  const int tid = threadIdx.x;
  const int s0 = blockIdx.x * 64;
  const int hk = blockIdx.y;
  const int b = blockIdx.z;
  const float s = fmaxf(__uint_as_float(slots[7]) / 127.0f, 1e-8f);
#pragma unroll
  for (int it = 0; it < 8; it++) {
    int idx = tid + it * 256;
    int sl = idx >> 5, c4 = idx & 31;
    float4 v = ((const float4*)(vbuf + ((size_t)(b * SEQ + s0 + sl) * NKV + hk) * HD))[c4];
    L[(c4 * 4 + 0) * 72 + sl] = f2bf(quantv(v.x, s));
    L[(c4 * 4 + 1) * 72 + sl] = f2bf(quantv(v.y, s));
    L[(c4 * 4 + 2) * 72 + sl] = f2bf(quantv(v.z, s));
    L[(c4 * 4 + 3) * 72 + sl] = f2bf(quantv(v.w, s));
  }
  __syncthreads();
  const size_t obase = ((size_t)(b * NKV + hk)) * HD * SEQ + s0;
#pragma unroll
  for (int it = 0; it < 4; it++) {
    int idx = tid + it * 256;
    int d = idx >> 3, sc = idx & 7;
    *(bf16x8*)(vbt + obase + (size_t)d * SEQ + sc * 8) = *(const bf16x8*)(&L[d * 72 + sc * 8]);
  }
}

// ---------------- MFMA GEMM body: 3-deep counted-vmcnt pipeline (T4) -------------
__device__ __forceinline__ void gemm_body(const unsigned short* __restrict__ A,
                                          const unsigned short* __restrict__ B,
                                          float* __restrict__ C, int N, int K, int m0, int n0,
                                          float sc, int amax_slot, unsigned int* slots) {
  __shared__ unsigned short As[3][128 * 32];
  __shared__ unsigned short Bs[3][128 * 32];
  const int tid = threadIdx.x;
  const int wave = tid >> 6, lane = tid & 63;
  const int l16 = lane & 15, quad = lane >> 4;
  const int wm = (wave & 1) * 64, wn = (wave >> 1) * 64;

  f32x4 acc[4][4];
#pragma unroll
  for (int i = 0; i < 4; i++)
#pragma unroll
    for (int j = 0; j < 4; j++) acc[i][j] = (f32x4){0.f, 0.f, 0.f, 0.f};

  auto STAGE = [&](int buf, int kt) {
#pragma unroll
    for (int it = 0; it < 2; it++) {
      int c = it * 256 + tid;
      int r = c >> 2, kc = (c & 3) * 8;
      gload_lds16(A + (size_t)(m0 + r) * K + kt + kc, &As[buf][(it * 256 + wave * 64) * 8]);
      gload_lds16(B + (size_t)(n0 + r) * K + kt + kc, &Bs[buf][(it * 256 + wave * 64) * 8]);
    }
  };

  const int nk = K / 32;  // K >= 96 always here
  STAGE(0, 0);
  STAGE(1, 32);
  STAGE(2, 64);
  for (int t = 0; t < nk; t++) {
    const int buf = t % 3;
    if (t + 3 < nk + 1)      asm volatile("s_waitcnt vmcnt(8)" ::: "memory");
    else if (t + 2 < nk + 1) asm volatile("s_waitcnt vmcnt(4)" ::: "memory");
    else                     asm volatile("s_waitcnt vmcnt(0)" ::: "memory");
    __builtin_amdgcn_sched_barrier(0);
    __builtin_amdgcn_s_barrier();  // buf[t] visible to all waves
    __builtin_amdgcn_sched_barrier(0);
    bf16x8 af[4], bq[4];
#pragma unroll
    for (int i = 0; i < 4; i++)
      af[i] = *(const bf16x8*)(&As[buf][(wm + i * 16 + l16) * 32 + quad * 8]);
#pragma unroll
    for (int j = 0; j < 4; j++)
      bq[j] = *(const bf16x8*)(&Bs[buf][(wn + j * 16 + l16) * 32 + quad * 8]);
    asm volatile("s_waitcnt lgkmcnt(0)" ::: "memory");
    __builtin_amdgcn_sched_barrier(0);
    __builtin_amdgcn_s_barrier();  // all waves done reading buf[t]; safe to overwrite
    __builtin_amdgcn_sched_barrier(0);
    if (t + 3 < nk) STAGE(buf, (t + 3) * 32);
#pragma unroll
    for (int i = 0; i < 4; i++)
#pragma unroll
      for (int j = 0; j < 4; j++)
        acc[i][j] = __builtin_amdgcn_mfma_f32_16x16x32_bf16(af[i], bq[j], acc[i][j], 0, 0, 0);
  }

  float am = 0.0f;
#pragma unroll
  for (int i = 0; i < 4; i++)
#pragma unroll
    for (int j = 0; j < 4; j++)
#pragma unroll
      for (int r = 0; r < 4; r++) {
        int row = m0 + wm + i * 16 + quad * 4 + r;
        int col = n0 + wn + j * 16 + l16;
        float v = acc[i][j][r] * sc;
        C[(size_t)row * N + col] = v;
        am = fmaxf(am, fabsf(v));
      }
  if (amax_slot >= 0) {
    __syncthreads();
    float* red = (float*)As;
    red[tid] = am;
    __syncthreads();
    for (int o = 128; o > 0; o >>= 1) {
      if (tid < o) red[tid] = fmaxf(red[tid], red[tid + o]);
      __syncthreads();
    }
    if (tid == 0) atomicMax(slots + amax_slot, __float_as_uint(red[0]));
  }
}

// Fused Q/K/V projection: shared A, per-block weight select.
__global__ __launch_bounds__(256) void gemm_qkv_k(const unsigned short* __restrict__ A,
                                                  const unsigned short* __restrict__ Bq,
                                                  const unsigned short* __restrict__ Bk,
                                                  const unsigned short* __restrict__ Bv,
                                                  float* __restrict__ Cq, float* __restrict__ Ck,
                                                  float* __restrict__ Cv,
                                                  unsigned int* __restrict__ slots) {
  const int nt = blockIdx.x, m0 = blockIdx.y * 128;
  const unsigned short* B;
  float* C;
  int N, n0, ib, amx;
  if (nt < 16) {
    B = Bq; C = Cq; N = 2048; n0 = nt * 128; ib = 1; amx = -1;
  } else if (nt < 20) {
    B = Bk; C = Ck; N = 512; n0 = (nt - 16) * 128; ib = 2; amx = -1;
  } else {
    B = Bv; C = Cv; N = 512; n0 = (nt - 20) * 128; ib = 3; amx = 7;
  }
  const float sc = slot_scale(slots, 0) * slot_scale(slots, ib);
  gemm_body(A, B, C, N, HID, m0, n0, sc, amx, slots);
}

__global__ __launch_bounds__(256) void gemm_o_k(const unsigned short* __restrict__ A,
                                                const unsigned short* __restrict__ B,
                                                float* __restrict__ C,
                                                unsigned int* __restrict__ slots) {
  const float sc = slot_scale(slots, 8) * slot_scale(slots, 4);
  gemm_body(A, B, C, HID, NH * HD, blockIdx.y * 128, blockIdx.x * 128, sc, -1, slots);
}

// ---------------- RoPE cos/sin table (computed once; exact libm) ----
__global__ __launch_bounds__(256) void rope_table_k(float2* __restrict__ tab) {
  int idx = blockIdx.x * 256 + threadIdx.x;  // 131072 total
  int i = idx & 63, s = idx >> 6;
  float inv = 1.0f / powf(10000.0f, (float)(2 * i) * (1.0f / 128.0f));
  float fr = (float)s * inv;
  tab[idx] = make_float2(cosf(fr), sinf(fr));
}

// ---------------- RoPE in-place + absmax ----------------
__global__ __launch_bounds__(256) void rope_kernel(float* __restrict__ t, int nh, int nhs,
                                                   const float2* __restrict__ tab,
                                                   unsigned int* __restrict__ slot) {
  const size_t total4 = (size_t)BATCH * SEQ * nh * 16;  // float4-pair items
  float am = 0.0f;
  for (size_t it = (size_t)blockIdx.x * 256 + threadIdx.x; it < total4;
       it += (size_t)gridDim.x * 256) {
    const int i4 = (int)(it & 15);
    const int h = (int)((it >> 4) & (nh - 1));
    const int s = (int)((it >> (4 + nhs)) & (SEQ - 1));
    const int b = (int)(it >> (15 + nhs));
    const size_t base = ((size_t)(b * SEQ + s) * nh + h) * HD + i4 * 4;
    float4 x1 = *(const float4*)(t + base);
    float4 x2 = *(const float4*)(t + base + 64);
    const float4* tp = (const float4*)(tab + (s << 6) + i4 * 4);
    float4 cs01 = tp[0];
    float4 cs23 = tp[1];
    float4 r1, r2;
    r1.x = x1.x * cs01.x - x2.x * cs01.y;  r2.x = x2.x * cs01.x + x1.x * cs01.y;
    r1.y = x1.y * cs01.z - x2.y * cs01.w;  r2.y = x2.y * cs01.z + x1.y * cs01.w;
    r1.z = x1.z * cs23.x - x2.z * cs23.y;  r2.z = x2.z * cs23.x + x1.z * cs23.y;
    r1.w = x1.w * cs23.z - x2.w * cs23.w;  r2.w = x2.w * cs23.z + x1.w * cs23.w;
    *(float4*)(t + base) = r1;
    *(float4*)(t + base + 64) = r2;
    am = fmaxf(am, fmaxf(amax4(r1), amax4(r2)));
  }
  block_amax_atomic(am, slot);
}

// ---------------- MFMA single-tile two-pass causal attention (key-sliced QK^T) ------------
// Identical to round 10 except __launch_bounds__(256, 2): round 10's (256,3) forced the
// allocator under a 170-VGPR cap and it SPILLED the 64-VGPR qf[] (WRITE_SIZE 33->93MB,
// dur 98->154us). (256,2) raises the cap to 256 (min-waves hint, not an occupancy cap; at
// 45KB LDS 3 blocks/CU still fit if allocation lands <=170). Clean test of the LDS-traffic
// theory: K-reads 256->64 B/thread/tile with no scratch traffic.
#define TK 64
#define KS_STRIDE (HD + 8)
#define VT_STRIDE (TK + 8)
#define PS_STRIDE (TK + 8)

__device__ __forceinline__ void ldK(bf16x8 r[4], const unsigned short* kb, int b, int hk,
                                    int j0, int tid) {
#pragma unroll
  for (int it = 0; it < 4; it++) {
    int c2 = tid + it * 256;
    int rr = c2 >> 4, c = c2 & 15;
    r[it] = *(const bf16x8*)(kb + ((size_t)(b * SEQ + j0 + rr) * NKV + hk) * HD + c * 8);
  }
}
__device__ __forceinline__ void stK(unsigned short* Ks, const bf16x8 r[4], int tid) {
#pragma unroll
  for (int it = 0; it < 4; it++) {
    int c2 = tid + it * 256;
    int rr = c2 >> 4, c = c2 & 15;
    *(bf16x8*)(&Ks[rr * KS_STRIDE + c * 8]) = r[it];
  }
}
__device__ __forceinline__ void ldV(bf16x8 r[4], const unsigned short* vbt, size_t vbase,
                                    int j0, int tid) {
#pragma unroll
  for (int it = 0; it < 4; it++) {
    int idx = tid + it * 256;
    int d = idx >> 3, sc = idx & 7;
    r[it] = *(const bf16x8*)(vbt + vbase + (size_t)d * SEQ + j0 + sc * 8);
  }
}
__device__ __forceinline__ void stV(unsigned short* Vt, const bf16x8 r[4], int tid) {
#pragma unroll
  for (int it = 0; it < 4; it++) {
    int idx = tid + it * 256;
    int d = idx >> 3, sc = idx & 7;
    *(bf16x8*)(&Vt[d * VT_STRIDE + sc * 8]) = r[it];
  }
}

// Load this wave's 16-key slice of the staged K tile (read ONCE, reused for all 4 rowgroups).
__device__ __forceinline__ void ldKf(bf16x8 kf[4], const unsigned short* Ks, int wave,
                                     int l16, int quad) {
  const unsigned short* kp = &Ks[(wave * 16 + l16) * KS_STRIDE + quad * 8];
#pragma unroll
  for (int s = 0; s < 4; s++) kf[s] = *(const bf16x8*)(kp + s * 32);
}
// One rowgroup's QK^T: S[key = wave*16 + quad*4 + r][qrow = g*16 + l16].
__device__ __forceinline__ f32x4 qk_g(const bf16x8 kf[4], const bf16x8* qfg) {
  f32x4 a = {0.f, 0.f, 0.f, 0.f};
#pragma unroll
  for (int s = 0; s < 4; s++)
    a = __builtin_amdgcn_mfma_f32_16x16x32_bf16(kf[s], qfg[s], a, 0, 0, 0);
  return a;
}
// PV: wave reads its own q-rows' P (written cross-wave; barrier before this).
__device__ __forceinline__ void pvacc1(f32x4 of[8], const unsigned short* Ps,
                                       const unsigned short* Vt, int wave, int l16, int quad) {
  const unsigned short* pp = &Ps[(wave * 16 + l16) * PS_STRIDE + quad * 8];
  bf16x8 p0 = *(const bf16x8*)pp;
  bf16x8 p1 = *(const bf16x8*)(pp + 32);
#pragma unroll
  for (int n = 0; n < 8; n++) {
    const unsigned short* vp = &Vt[(n * 16 + l16) * VT_STRIDE + quad * 8];
    of[n] = __builtin_amdgcn_mfma_f32_16x16x32_bf16(p0, *(const bf16x8*)vp, of[n], 0, 0, 0);
    of[n] = __builtin_amdgcn_mfma_f32_16x16x32_bf16(p1, *(const bf16x8*)(vp + 32), of[n],
                                                    0, 0, 0);
  }
}

__global__ __launch_bounds__(256, 2) void attn_mfma_kernel(const unsigned short* __restrict__ qb,
                                                           const unsigned short* __restrict__ kb,
                                                           const unsigned short* __restrict__ vbt,
                                                           float* __restrict__ ob,
                                                           unsigned int* __restrict__ slots) {
  __shared__ unsigned short Ks[TK * KS_STRIDE];   // 17408 B
  __shared__ unsigned short Vt[HD * VT_STRIDE];   // 18432 B
  __shared__ unsigned short Ps[64 * PS_STRIDE];   //  9216 B  (total 45056)

  const int tid = threadIdx.x;
  const int wave = tid >> 6;
  const int lane = tid & 63;
  const int l16 = lane & 15;
  const int quad = lane >> 4;
  // XCD swizzle: id&7 -> (b,hk); big causal tiles dispatch first.
  const int id = blockIdx.x;
  const int b = (id & 7) >> 2;
  const int hk = id & 3;
  const int j = id >> 3;               // 0..127
  const int h = hk * GROUPS + (j & 3);
  const int tile = 31 - (j >> 2);      // 31..0
  const int q0 = tile * 64, nt = tile + 1;

  const float s_q = slot_scale(slots, 5);
  const float s_k = slot_scale(slots, 6);
  const float s_v = slot_scale(slots, 7);
  const float ss = s_q * s_k / 11.313708498984761f;  // /sqrt(128)
  const float c1 = ss * LOG2E;
  const float scale_p = 1.0f / 127.0f;
  const size_t vbase = ((size_t)(b * NKV + hk)) * HD * SEQ;

  // Q for ALL 64 rows of this block's tile: qf[g*4+s], g = rowgroup, s = K-dim chunk.
  bf16x8 qf[16];
#pragma unroll
  for (int g = 0; g < 4; g++) {
    const unsigned short* qp =
        qb + ((size_t)(b * SEQ + q0 + g * 16 + l16) * NH + h) * HD + quad * 8;
#pragma unroll
    for (int s = 0; s < 4; s++) qf[g * 4 + s] = *(const bf16x8*)(qp + s * 32);
  }
  const int qrb = q0 + wave * 16 + quad * 4;  // epilogue rows (PV output, unchanged)

  // ---- Pass A: l sums (key-sliced; thread accumulates 4 rowgroups) ----
  float l[4] = {0.f, 0.f, 0.f, 0.f};
  bf16x8 kreg[4];
  ldK(kreg, kb, b, hk, 0, tid);
  for (int t = 0; t < nt; t++) {
    __syncthreads();
    stK(Ks, kreg, tid);
    if (t + 1 < nt) ldK(kreg, kb, b, hk, (t + 1) * TK, tid);
    __syncthreads();
    bf16x8 kf[4];
    ldKf(kf, Ks, wave, l16, quad);
    const bool diag = (t == nt - 1);
    const int key0 = t * TK + wave * 16 + quad * 4;
#pragma unroll
    for (int g = 0; g < 4; g++) {
      f32x4 a = qk_g(kf, &qf[g * 4]);
      if (!diag) {
#pragma unroll
        for (int r = 0; r < 4; r++)
          l[g] += __builtin_amdgcn_exp2f(fminf(a[r] * c1, CLAMP_L2));
      } else {
        const int qrow = q0 + g * 16 + l16;
#pragma unroll
        for (int r = 0; r < 4; r++) {
          float e = __builtin_amdgcn_exp2f(fminf(a[r] * c1, CLAMP_L2));
          l[g] += (key0 + r <= qrow) ? e : 0.0f;
        }
      }
    }
  }
  // reduce: quads (same wave, same qrow, different keys) then across waves (different slices)
#pragma unroll
  for (int g = 0; g < 4; g++) {
    l[g] += __shfl_xor(l[g], 16);
    l[g] += __shfl_xor(l[g], 32);
  }
  {
    float* Lr = (float*)Ps;  // 4 waves x 4 g x 16 rows = 1KB scratch
    if (quad == 0) {
#pragma unroll
      for (int g = 0; g < 4; g++) Lr[wave * 64 + g * 16 + l16] = l[g];
    }
    __syncthreads();
#pragma unroll
    for (int g = 0; g < 4; g++) {
      float s = Lr[g * 16 + l16] + Lr[64 + g * 16 + l16] + Lr[128 + g * 16 + l16] +
                Lr[192 + g * 16 + l16];
      l[g] = __log2f(127.0f / fmaxf(s, 1e-30f));  // reuse l[] as l2il[]
    }
  }

  // ---- Pass B: recompute S (key-sliced), quantize P, PV ----
  f32x4 of[8];
#pragma unroll
  for (int n = 0; n < 8; n++) of[n] = (f32x4){0.f, 0.f, 0.f, 0.f};
  bf16x8 vreg[4];
  ldK(kreg, kb, b, hk, 0, tid);
  ldV(vreg, vbt, vbase, 0, tid);
  for (int t = 0; t < nt; t++) {
    __syncthreads();  // also guarantees Lr reads / prev pvacc done before Ps overwrite
    stK(Ks, kreg, tid);
    stV(Vt, vreg, tid);
    if (t + 1 < nt) {
      ldK(kreg, kb, b, hk, (t + 1) * TK, tid);
      ldV(vreg, vbt, vbase, (t + 1) * TK, tid);
    }
    __syncthreads();
    bf16x8 kf[4];
    ldKf(kf, Ks, wave, l16, quad);
    const bool diag = (t == nt - 1);
    const int key0 = t * TK + wave * 16 + quad * 4;
#pragma unroll
    for (int g = 0; g < 4; g++) {
      f32x4 a = qk_g(kf, &qf[g * 4]);
      float p0 = rintf(__builtin_amdgcn_exp2f(fminf(a[0] * c1, CLAMP_L2) + l[g]));
      float p1 = rintf(__builtin_amdgcn_exp2f(fminf(a[1] * c1, CLAMP_L2) + l[g]));
      float p2 = rintf(__builtin_amdgcn_exp2f(fminf(a[2] * c1, CLAMP_L2) + l[g]));
      float p3 = rintf(__builtin_amdgcn_exp2f(fminf(a[3] * c1, CLAMP_L2) + l[g]));
      if (diag) {
        const int qrow = q0 + g * 16 + l16;
        if (key0 + 0 > qrow) p0 = 0.0f;
        if (key0 + 1 > qrow) p1 = 0.0f;
        if (key0 + 2 > qrow) p2 = 0.0f;
        if (key0 + 3 > qrow) p3 = 0.0f;
      }
      ushort4 pk;
      pk.x = f2bf(p0);
      pk.y = f2bf(p1);
      pk.z = f2bf(p2);
      pk.w = f2bf(p3);
      *(ushort4*)(&Ps[(g * 16 + l16) * PS_STRIDE + wave * 16 + quad * 4]) = pk;
    }
    __syncthreads();  // P written cross-wave; make visible before PV
    pvacc1(of, Ps, Vt, wave, l16, quad);
  }

  // ---- epilogue ----
  const float oscale = scale_p * s_v;
  float amax = 0.0f;
#pragma unroll
  for (int n = 0; n < 8; n++)
#pragma unroll
    for (int r = 0; r < 4; r++) {
      float v = of[n][r] * oscale;
      ob[((size_t)(b * SEQ + qrb + r) * NH + h) * HD + n * 16 + l16] = v;
      amax = fmaxf(amax, fabsf(v));
    }
  // amax reduction reusing Ps as scratch
  __syncthreads();
  float* red = (float*)Ps;
  red[tid] = amax;
  __syncthreads();
  for (int o = 128; o > 0; o >>= 1) {
    if (tid < o) red[tid] = fmaxf(red[tid], red[tid + o]);
    __syncthreads();
  }
  if (tid == 0) atomicMax(slots + 8, __float_as_uint(red[0]));
}

extern "C" void kernel_launch(void* const* d_in, const int* in_sizes, int n_in,
                              void* d_out, int out_size, void* d_ws, size_t ws_size,
                              hipStream_t stream) {
  const float* hs = (const float*)d_in[0];
  const float* wq = (const float*)d_in[3];
  const float* wk = (const float*)d_in[4];
  const float* wv = (const float*)d_in[5];
  const float* wo = (const float*)d_in[6];
  float* out = (float*)d_out;

  unsigned int* slots = (unsigned int*)d_ws;
  char* p = (char*)d_ws + 256;
  unsigned short* hsq = (unsigned short*)p;  p += 2 * N_HS;  // dead after QKV GEMM
  unsigned short* wqq = (unsigned short*)p;  p += 2 * N_WQ;
  unsigned short* wkq = (unsigned short*)p;  p += 2 * N_WKV;
  unsigned short* wvq = (unsigned short*)p;  p += 2 * N_WKV;
  unsigned short* woq = (unsigned short*)p;  p += 2 * N_WO;
  float* kbuf = (float*)p;                   p += 4 * N_KV;
  float* vbuf = (float*)p;                   p += 4 * N_KV;
  unsigned short* qbf = (unsigned short*)p;  p += 2 * N_Q;
  unsigned short* kbf = (unsigned short*)p;  p += 2 * N_KV;
  unsigned short* vbt = (unsigned short*)p;  p += 2 * N_KV;  // transposed quantized V
  float2* rtab = (float2*)p;                 // RoPE cos/sin table, 1MB
  unsigned short* aobf = hsq;  // alias: hsq dead after QKV GEMM
  float* qbuf = out;           // fp32 q-proj output lives in d_out
  float* aobuf = out;          // fp32 attn output lives in d_out

  hipMemsetAsync(d_ws, 0, 256, stream);

  // slots: 0=x 1=wq 2=wk 3=wv 4=wo 5=q 6=k 7=v 8=ao
  rope_table_k<<<(SEQ * 64) / 256, 256, 0, stream>>>(rtab);
  absmax5_k<<<dim3(256, 5), 256, 0, stream>>>(hs, wq, wk, wv, wo, slots);
  quant5_k<<<dim3(256, 5), 256, 0, stream>>>(hs, wq, wk, wv, wo, slots, hsq, wqq, wkq, wvq, woq);

  const int M = BATCH * SEQ;
  gemm_qkv_k<<<dim3(24, M / 128), 256, 0, stream>>>(hsq, wqq, wkq, wvq, qbuf, kbuf, vbuf, slots);

  rope_kernel<<<1024, 256, 0, stream>>>(qbuf, NH, 4, rtab, slots + 5);
  rope_kernel<<<256, 256, 0, stream>>>(kbuf, NKV, 2, rtab, slots + 6);

  quant2_k<<<dim3(256, 2), 256, 0, stream>>>(qbuf, kbuf, slots, qbf, kbf);
  vtq_k<<<dim3(SEQ / 64, NKV, BATCH), 256, 0, stream>>>(vbuf, slots, vbt);

  attn_mfma_kernel<<<dim3(1024, 1, 1), 256, 0, stream>>>(qbf, kbf, vbt, aobuf, slots);

  quant1_k<<<256, 256, 0, stream>>>(aobuf, N_Q / 4, slots + 8, aobf);

  gemm_o_k<<<dim3(HID / 128, M / 128), 256, 0, stream>>>(aobf, woq, out, slots);
}

// Round 12
// 410.451 us; speedup vs baseline: 1.2117x; 1.0148x over previous
//
#include <hip/hip_runtime.h>
#include <math.h>
#include <stdint.h>
#include <stddef.h>

#define HID 2048
#define NH 16
#define NKV 4
#define HD 128
#define GROUPS (NH / NKV)
#define BATCH 2
#define SEQ 2048

#define N_HS  8388608ull
#define N_Q   8388608ull
#define N_KV  2097152ull
#define N_WQ  4194304ull
#define N_WKV 1048576ull
#define N_WO  4194304ull

typedef __attribute__((ext_vector_type(8))) short bf16x8;
typedef __attribute__((ext_vector_type(4))) float f32x4;

#define LOG2E 1.4426950408889634f
#define CLAMP_L2 115.41560325f  // 80 * log2(e)

__device__ inline float quantv(float x, float s) {
  float q = rintf(x / s);
  return fminf(fmaxf(q, -128.0f), 127.0f);
}

__device__ inline float slot_scale(const unsigned int* slots, int i) {
  return fmaxf(__uint_as_float(slots[i]) / 127.0f, 1e-8f);
}

__device__ inline unsigned short f2bf(float x) {
  return (unsigned short)(__float_as_uint(x) >> 16);
}

__device__ inline float amax4(float4 v) {
  return fmaxf(fmaxf(fabsf(v.x), fabsf(v.y)), fmaxf(fabsf(v.z), fabsf(v.w)));
}

__device__ inline void block_amax_atomic(float m, unsigned int* slot) {
  __shared__ float red[256];
  red[threadIdx.x] = m;
  __syncthreads();
  for (int o = 128; o > 0; o >>= 1) {
    if (threadIdx.x < o) red[threadIdx.x] = fmaxf(red[threadIdx.x], red[threadIdx.x + o]);
    __syncthreads();
  }
  if (threadIdx.x == 0) atomicMax(slot, __float_as_uint(red[0]));
}

// async global -> LDS, 16B per lane (dest = wave-uniform base + lane*16)
__device__ __forceinline__ void gload_lds16(const void* g, void* l) {
  __builtin_amdgcn_global_load_lds((const __attribute__((address_space(1))) unsigned int*)g,
                                   (__attribute__((address_space(3))) unsigned int*)l, 16, 0, 0);
}

// ---------------- fused absmax over the 5 input tensors + RoPE table (slice 5) ------------
// tab[(s<<6)+i] = {cos(s*inv_freq_i), sin(s*inv_freq_i)}; folded in here because the table
// kernel ran serially at stream head (~5us + launch gap) with zero dependencies, while this
// pass is BW-bound with an idle VALU. Branch is block-uniform (t constant per block).
__global__ __launch_bounds__(256) void absmax5_k(const float* __restrict__ a0,
                                                 const float* __restrict__ a1,
                                                 const float* __restrict__ a2,
                                                 const float* __restrict__ a3,
                                                 const float* __restrict__ a4,
                                                 float2* __restrict__ tab,
                                                 unsigned int* __restrict__ slots) {
  const int t = blockIdx.y;
  if (t == 5) {  // rope cos/sin table: 131072 entries over 256 blocks x 256 threads
    for (int idx = blockIdx.x * 256 + threadIdx.x; idx < SEQ * 64; idx += 256 * 256) {
      int i = idx & 63, s = idx >> 6;
      float inv = 1.0f / powf(10000.0f, (float)(2 * i) * (1.0f / 128.0f));
      float fr = (float)s * inv;
      tab[idx] = make_float2(cosf(fr), sinf(fr));
    }
    return;
  }
  const float* x = t == 0 ? a0 : t == 1 ? a1 : t == 2 ? a2 : t == 3 ? a3 : a4;
  const size_t n4 = (t == 0 ? N_HS : t == 1 ? N_WQ : t == 2 ? N_WKV : t == 3 ? N_WKV : N_WO) / 4;
  const float4* xp = (const float4*)x;
  float m = 0.0f;
  for (size_t i = (size_t)blockIdx.x * 256 + threadIdx.x; i < n4; i += (size_t)gridDim.x * 256)
    m = fmaxf(m, amax4(xp[i]));
  block_amax_atomic(m, slots + t);
}

// ---------------- fused quantize over 5 tensors ----------------
__global__ __launch_bounds__(256) void quant5_k(const float* __restrict__ a0,
                                                const float* __restrict__ a1,
                                                const float* __restrict__ a2,
                                                const float* __restrict__ a3,
                                                const float* __restrict__ a4,
                                                const unsigned int* __restrict__ slots,
                                                unsigned short* __restrict__ o0,
                                                unsigned short* __restrict__ o1,
                                                unsigned short* __restrict__ o2,
                                                unsigned short* __restrict__ o3,
                                                unsigned short* __restrict__ o4) {
  const int t = blockIdx.y;
  const float* x = t == 0 ? a0 : t == 1 ? a1 : t == 2 ? a2 : t == 3 ? a3 : a4;
  unsigned short* o = t == 0 ? o0 : t == 1 ? o1 : t == 2 ? o2 : t == 3 ? o3 : o4;
  const size_t n4 = (t == 0 ? N_HS : t == 1 ? N_WQ : t == 2 ? N_WKV : t == 3 ? N_WKV : N_WO) / 4;
  const float s = fmaxf(__uint_as_float(slots[t]) / 127.0f, 1e-8f);
  const float4* xp = (const float4*)x;
  ushort4* op = (ushort4*)o;
  for (size_t i = (size_t)blockIdx.x * 256 + threadIdx.x; i < n4; i += (size_t)gridDim.x * 256) {
    float4 v = xp[i];
    ushort4 r;
    r.x = f2bf(quantv(v.x, s));
    r.y = f2bf(quantv(v.y, s));
    r.z = f2bf(quantv(v.z, s));
    r.w = f2bf(quantv(v.w, s));
    op[i] = r;
  }
}

// ---------------- fused quantize q/k ----------------
__global__ __launch_bounds__(256) void quant2_k(const float* __restrict__ a0,
                                                const float* __restrict__ a1,
                                                const unsigned int* __restrict__ slots,
                                                unsigned short* __restrict__ o0,
                                                unsigned short* __restrict__ o1) {
  const int t = blockIdx.y;
  const float* x = t == 0 ? a0 : a1;
  unsigned short* o = t == 0 ? o0 : o1;
  const size_t n4 = (t == 0 ? N_Q : N_KV) / 4;
  const float s = fmaxf(__uint_as_float(slots[5 + t]) / 127.0f, 1e-8f);
  const float4* xp = (const float4*)x;
  ushort4* op = (ushort4*)o;
  for (size_t i = (size_t)blockIdx.x * 256 + threadIdx.x; i < n4; i += (size_t)gridDim.x * 256) {
    float4 v = xp[i];
    ushort4 r;
    r.x = f2bf(quantv(v.x, s));
    r.y = f2bf(quantv(v.y, s));
    r.z = f2bf(quantv(v.z, s));
    r.w = f2bf(quantv(v.w, s));
    op[i] = r;
  }
}

__global__ __launch_bounds__(256) void quant1_k(const float* __restrict__ x, size_t n4,
                                                const unsigned int* __restrict__ slot,
                                                unsigned short* __restrict__ out) {
  const float s = fmaxf(__uint_as_float(*slot) / 127.0f, 1e-8f);
  const float4* xp = (const float4*)x;
  ushort4* op = (ushort4*)out;
  for (size_t i = (size_t)blockIdx.x * 256 + threadIdx.x; i < n4; i += (size_t)gridDim.x * 256) {
    float4 v = xp[i];
    ushort4 r;
    r.x = f2bf(quantv(v.x, s));
    r.y = f2bf(quantv(v.y, s));
    r.z = f2bf(quantv(v.z, s));
    r.w = f2bf(quantv(v.w, s));
    op[i] = r;
  }
}

// ---------------- V: quantize + transpose to [b][hk][d][s] ----------------
__global__ __launch_bounds__(256) void vtq_k(const float* __restrict__ vbuf,
                                             const unsigned int* __restrict__ slots,
                                             unsigned short* __restrict__ vbt) {
  __shared__ unsigned short L[128 * 72];
  const int tid = threadIdx.x;
  const int s0 = blockIdx.x * 64;
  const int hk = blockIdx.y;
  const int b = blockIdx.z;
  const float s = fmaxf(__uint_as_float(slots[7]) / 127.0f, 1e-8f);
#pragma unroll
  for (int it = 0; it < 8; it++) {
    int idx = tid + it * 256;
    int sl = idx >> 5, c4 = idx & 31;
    float4 v = ((const float4*)(vbuf + ((size_t)(b * SEQ + s0 + sl) * NKV + hk) * HD))[c4];
    L[(c4 * 4 + 0) * 72 + sl] = f2bf(quantv(v.x, s));
    L[(c4 * 4 + 1) * 72 + sl] = f2bf(quantv(v.y, s));
    L[(c4 * 4 + 2) * 72 + sl] = f2bf(quantv(v.z, s));
    L[(c4 * 4 + 3) * 72 + sl] = f2bf(quantv(v.w, s));
  }
  __syncthreads();
  const size_t obase = ((size_t)(b * NKV + hk)) * HD * SEQ + s0;
#pragma unroll
  for (int it = 0; it < 4; it++) {
    int idx = tid + it * 256;
    int d = idx >> 3, sc = idx & 7;
    *(bf16x8*)(vbt + obase + (size_t)d * SEQ + sc * 8) = *(const bf16x8*)(&L[d * 72 + sc * 8]);
  }
}

// ---------------- MFMA GEMM body: 3-deep counted-vmcnt pipeline (T4) -------------
__device__ __forceinline__ void gemm_body(const unsigned short* __restrict__ A,
                                          const unsigned short* __restrict__ B,
                                          float* __restrict__ C, int N, int K, int m0, int n0,
                                          float sc, int amax_slot, unsigned int* slots) {
  __shared__ unsigned short As[3][128 * 32];
  __shared__ unsigned short Bs[3][128 * 32];
  const int tid = threadIdx.x;
  const int wave = tid >> 6, lane = tid & 63;
  const int l16 = lane & 15, quad = lane >> 4;
  const int wm = (wave & 1) * 64, wn = (wave >> 1) * 64;

  f32x4 acc[4][4];
#pragma unroll
  for (int i = 0; i < 4; i++)
#pragma unroll
    for (int j = 0; j < 4; j++) acc[i][j] = (f32x4){0.f, 0.f, 0.f, 0.f};

  auto STAGE = [&](int buf, int kt) {
#pragma unroll
    for (int it = 0; it < 2; it++) {
      int c = it * 256 + tid;
      int r = c >> 2, kc = (c & 3) * 8;
      gload_lds16(A + (size_t)(m0 + r) * K + kt + kc, &As[buf][(it * 256 + wave * 64) * 8]);
      gload_lds16(B + (size_t)(n0 + r) * K + kt + kc, &Bs[buf][(it * 256 + wave * 64) * 8]);
    }
  };

  const int nk = K / 32;  // K >= 96 always here
  STAGE(0, 0);
  STAGE(1, 32);
  STAGE(2, 64);
  for (int t = 0; t < nk; t++) {
    const int buf = t % 3;
    if (t + 3 < nk + 1)      asm volatile("s_waitcnt vmcnt(8)" ::: "memory");
    else if (t + 2 < nk + 1) asm volatile("s_waitcnt vmcnt(4)" ::: "memory");
    else                     asm volatile("s_waitcnt vmcnt(0)" ::: "memory");
    __builtin_amdgcn_sched_barrier(0);
    __builtin_amdgcn_s_barrier();  // buf[t] visible to all waves
    __builtin_amdgcn_sched_barrier(0);
    bf16x8 af[4], bq[4];
#pragma unroll
    for (int i = 0; i < 4; i++)
      af[i] = *(const bf16x8*)(&As[buf][(wm + i * 16 + l16) * 32 + quad * 8]);
#pragma unroll
    for (int j = 0; j < 4; j++)
      bq[j] = *(const bf16x8*)(&Bs[buf][(wn + j * 16 + l16) * 32 + quad * 8]);
    asm volatile("s_waitcnt lgkmcnt(0)" ::: "memory");
    __builtin_amdgcn_sched_barrier(0);
    __builtin_amdgcn_s_barrier();  // all waves done reading buf[t]; safe to overwrite
    __builtin_amdgcn_sched_barrier(0);
    if (t + 3 < nk) STAGE(buf, (t + 3) * 32);
#pragma unroll
    for (int i = 0; i < 4; i++)
#pragma unroll
      for (int j = 0; j < 4; j++)
        acc[i][j] = __builtin_amdgcn_mfma_f32_16x16x32_bf16(af[i], bq[j], acc[i][j], 0, 0, 0);
  }

  float am = 0.0f;
#pragma unroll
  for (int i = 0; i < 4; i++)
#pragma unroll
    for (int j = 0; j < 4; j++)
#pragma unroll
      for (int r = 0; r < 4; r++) {
        int row = m0 + wm + i * 16 + quad * 4 + r;
        int col = n0 + wn + j * 16 + l16;
        float v = acc[i][j][r] * sc;
        C[(size_t)row * N + col] = v;
        am = fmaxf(am, fabsf(v));
      }
  if (amax_slot >= 0) {
    __syncthreads();
    float* red = (float*)As;
    red[tid] = am;
    __syncthreads();
    for (int o = 128; o > 0; o >>= 1) {
      if (tid < o) red[tid] = fmaxf(red[tid], red[tid + o]);
      __syncthreads();
    }
    if (tid == 0) atomicMax(slots + amax_slot, __float_as_uint(red[0]));
  }
}

// Fused Q/K/V projection: shared A, per-block weight select.
__global__ __launch_bounds__(256) void gemm_qkv_k(const unsigned short* __restrict__ A,
                                                  const unsigned short* __restrict__ Bq,
                                                  const unsigned short* __restrict__ Bk,
                                                  const unsigned short* __restrict__ Bv,
                                                  float* __restrict__ Cq, float* __restrict__ Ck,
                                                  float* __restrict__ Cv,
                                                  unsigned int* __restrict__ slots) {
  const int nt = blockIdx.x, m0 = blockIdx.y * 128;
  const unsigned short* B;
  float* C;
  int N, n0, ib, amx;
  if (nt < 16) {
    B = Bq; C = Cq; N = 2048; n0 = nt * 128; ib = 1; amx = -1;
  } else if (nt < 20) {
    B = Bk; C = Ck; N = 512; n0 = (nt - 16) * 128; ib = 2; amx = -1;
  } else {
    B = Bv; C = Cv; N = 512; n0 = (nt - 20) * 128; ib = 3; amx = 7;
  }
  const float sc = slot_scale(slots, 0) * slot_scale(slots, ib);
  gemm_body(A, B, C, N, HID, m0, n0, sc, amx, slots);
}

__global__ __launch_bounds__(256) void gemm_o_k(const unsigned short* __restrict__ A,
                                                const unsigned short* __restrict__ B,
                                                float* __restrict__ C,
                                                unsigned int* __restrict__ slots) {
  const float sc = slot_scale(slots, 8) * slot_scale(slots, 4);
  gemm_body(A, B, C, HID, NH * HD, blockIdx.y * 128, blockIdx.x * 128, sc, -1, slots);
}

// ---------------- RoPE in-place + absmax ----------------
__global__ __launch_bounds__(256) void rope_kernel(float* __restrict__ t, int nh, int nhs,
                                                   const float2* __restrict__ tab,
                                                   unsigned int* __restrict__ slot) {
  const size_t total4 = (size_t)BATCH * SEQ * nh * 16;  // float4-pair items
  float am = 0.0f;
  for (size_t it = (size_t)blockIdx.x * 256 + threadIdx.x; it < total4;
       it += (size_t)gridDim.x * 256) {
    const int i4 = (int)(it & 15);
    const int h = (int)((it >> 4) & (nh - 1));
    const int s = (int)((it >> (4 + nhs)) & (SEQ - 1));
    const int b = (int)(it >> (15 + nhs));
    const size_t base = ((size_t)(b * SEQ + s) * nh + h) * HD + i4 * 4;
    float4 x1 = *(const float4*)(t + base);
    float4 x2 = *(const float4*)(t + base + 64);
    const float4* tp = (const float4*)(tab + (s << 6) + i4 * 4);
    float4 cs01 = tp[0];
    float4 cs23 = tp[1];
    float4 r1, r2;
    r1.x = x1.x * cs01.x - x2.x * cs01.y;  r2.x = x2.x * cs01.x + x1.x * cs01.y;
    r1.y = x1.y * cs01.z - x2.y * cs01.w;  r2.y = x2.y * cs01.z + x1.y * cs01.w;
    r1.z = x1.z * cs23.x - x2.z * cs23.y;  r2.z = x2.z * cs23.x + x1.z * cs23.y;
    r1.w = x1.w * cs23.z - x2.w * cs23.w;  r2.w = x2.w * cs23.z + x1.w * cs23.w;
    *(float4*)(t + base) = r1;
    *(float4*)(t + base + 64) = r2;
    am = fmaxf(am, fmaxf(amax4(r1), amax4(r2)));
  }
  block_amax_atomic(am, slot);
}

// ---------------- MFMA single-tile two-pass causal attention (swapped QK^T) ----------------
// Round-8 version restored verbatim: 1024 blocks, 64 q-rows/block, descending tiles,
// (256,3) @ 45KB LDS -> 3 blocks/CU, VGPR 80, 98.5us. Rounds 9/10/11 (dual-group,
// key-sliced x2) all lost to it: dual-group halved parallelism; key-slicing's LDS-traffic
// win was offset by a 3rd barrier + occupancy drop. This structure is the local optimum.
#define TK 64
#define KS_STRIDE (HD + 8)
#define VT_STRIDE (TK + 8)
#define PS_STRIDE (TK + 8)

__device__ __forceinline__ void ldK(bf16x8 r[4], const unsigned short* kb, int b, int hk,
                                    int j0, int tid) {
#pragma unroll
  for (int it = 0; it < 4; it++) {
    int c2 = tid + it * 256;
    int rr = c2 >> 4, c = c2 & 15;
    r[it] = *(const bf16x8*)(kb + ((size_t)(b * SEQ + j0 + rr) * NKV + hk) * HD + c * 8);
  }
}
__device__ __forceinline__ void stK(unsigned short* Ks, const bf16x8 r[4], int tid) {
#pragma unroll
  for (int it = 0; it < 4; it++) {
    int c2 = tid + it * 256;
    int rr = c2 >> 4, c = c2 & 15;
    *(bf16x8*)(&Ks[rr * KS_STRIDE + c * 8]) = r[it];
  }
}
__device__ __forceinline__ void ldV(bf16x8 r[4], const unsigned short* vbt, size_t vbase,
                                    int j0, int tid) {
#pragma unroll
  for (int it = 0; it < 4; it++) {
    int idx = tid + it * 256;
    int d = idx >> 3, sc = idx & 7;
    r[it] = *(const bf16x8*)(vbt + vbase + (size_t)d * SEQ + j0 + sc * 8);
  }
}
__device__ __forceinline__ void stV(unsigned short* Vt, const bf16x8 r[4], int tid) {
#pragma unroll
  for (int it = 0; it < 4; it++) {
    int idx = tid + it * 256;
    int d = idx >> 3, sc = idx & 7;
    *(bf16x8*)(&Vt[d * VT_STRIDE + sc * 8]) = r[it];
  }
}

// Swapped QK^T: thread holds S[key = j0 + kt*16 + quad*4 + r][q-row = wave*16 + l16].
__device__ __forceinline__ void qk41(f32x4 sfr[4], const unsigned short* Ks,
                                     const bf16x8 qf[4], int l16, int quad) {
#pragma unroll
  for (int kt = 0; kt < 4; kt++) {
    f32x4 a = {0.f, 0.f, 0.f, 0.f};
    const unsigned short* kp = &Ks[(kt * 16 + l16) * KS_STRIDE + quad * 8];
#pragma unroll
    for (int s = 0; s < 4; s++)
      a = __builtin_amdgcn_mfma_f32_16x16x32_bf16(*(const bf16x8*)(kp + s * 32), qf[s], a,
                                                  0, 0, 0);
    sfr[kt] = a;
  }
}
// l += sum of e over this tile's 16 keys (thread-local row = qrow).
__device__ __forceinline__ void lacc(float& l, const f32x4 sfr[4], float c1, bool diag,
                                     int j0, int qrow, int quad) {
  if (!diag) {
#pragma unroll
    for (int kt = 0; kt < 4; kt++)
#pragma unroll
      for (int r = 0; r < 4; r++)
        l += __builtin_amdgcn_exp2f(fminf(sfr[kt][r] * c1, CLAMP_L2));
  } else {
#pragma unroll
    for (int kt = 0; kt < 4; kt++) {
      const int key0 = j0 + kt * 16 + quad * 4;
#pragma unroll
      for (int r = 0; r < 4; r++) {
        float e = __builtin_amdgcn_exp2f(fminf(sfr[kt][r] * c1, CLAMP_L2));
        l += (key0 + r <= qrow) ? e : 0.0f;
      }
    }
  }
}
// Quantize P and write 4 consecutive keys per b64.
__device__ __forceinline__ void pquant(unsigned short* Psb, const f32x4 sfr[4],
                                       float l2il, float c1, bool diag, int j0,
                                       int qrow, int wave, int l16, int quad) {
  unsigned short* rowp = &Psb[(wave * 16 + l16) * PS_STRIDE + quad * 4];
#pragma unroll
  for (int kt = 0; kt < 4; kt++) {
    const int key0 = j0 + kt * 16 + quad * 4;
    float p0 = rintf(__builtin_amdgcn_exp2f(fminf(sfr[kt][0] * c1, CLAMP_L2) + l2il));
    float p1 = rintf(__builtin_amdgcn_exp2f(fminf(sfr[kt][1] * c1, CLAMP_L2) + l2il));
    float p2 = rintf(__builtin_amdgcn_exp2f(fminf(sfr[kt][2] * c1, CLAMP_L2) + l2il));
    float p3 = rintf(__builtin_amdgcn_exp2f(fminf(sfr[kt][3] * c1, CLAMP_L2) + l2il));
    if (diag) {
      if (key0 + 0 > qrow) p0 = 0.0f;
      if (key0 + 1 > qrow) p1 = 0.0f;
      if (key0 + 2 > qrow) p2 = 0.0f;
      if (key0 + 3 > qrow) p3 = 0.0f;
    }
    ushort4 pk;
    pk.x = f2bf(p0);
    pk.y = f2bf(p1);
    pk.z = f2bf(p2);
    pk.w = f2bf(p3);
    *(ushort4*)(rowp + kt * 16) = pk;
  }
}
// PV: one P row fragment x 8 V-column tiles.
__device__ __forceinline__ void pvacc1(f32x4 of[8], const unsigned short* Ps,
                                       const unsigned short* Vt, int wave, int l16, int quad) {
  const unsigned short* pp = &Ps[(wave * 16 + l16) * PS_STRIDE + quad * 8];
  bf16x8 p0 = *(const bf16x8*)pp;
  bf16x8 p1 = *(const bf16x8*)(pp + 32);
#pragma unroll
  for (int n = 0; n < 8; n++) {
    const unsigned short* vp = &Vt[(n * 16 + l16) * VT_STRIDE + quad * 8];
    of[n] = __builtin_amdgcn_mfma_f32_16x16x32_bf16(p0, *(const bf16x8*)vp, of[n], 0, 0, 0);
    of[n] = __builtin_amdgcn_mfma_f32_16x16x32_bf16(p1, *(const bf16x8*)(vp + 32), of[n],
                                                    0, 0, 0);
  }
}

__global__ __launch_bounds__(256, 3) void attn_mfma_kernel(const unsigned short* __restrict__ qb,
                                                           const unsigned short* __restrict__ kb,
                                                           const unsigned short* __restrict__ vbt,
                                                           float* __restrict__ ob,
                                                           unsigned int* __restrict__ slots) {
  __shared__ unsigned short Ks[TK * KS_STRIDE];   // 17408 B
  __shared__ unsigned short Vt[HD * VT_STRIDE];   // 18432 B
  __shared__ unsigned short Ps[64 * PS_STRIDE];   //  9216 B  (total 45056 -> 3 blocks/CU)

  const int tid = threadIdx.x;
  const int wave = tid >> 6;
  const int lane = tid & 63;
  const int l16 = lane & 15;
  const int quad = lane >> 4;
  // XCD swizzle: id&7 -> (b,hk); big causal tiles dispatch first.
  const int id = blockIdx.x;
  const int b = (id & 7) >> 2;
  const int hk = id & 3;
  const int j = id >> 3;               // 0..127
  const int h = hk * GROUPS + (j & 3);
  const int tile = 31 - (j >> 2);      // 31..0: big causal tiles dispatch first
  const int q0 = tile * 64, nt = tile + 1;

  const float s_q = slot_scale(slots, 5);
  const float s_k = slot_scale(slots, 6);
  const float s_v = slot_scale(slots, 7);
  const float ss = s_q * s_k / 11.313708498984761f;  // /sqrt(128)
  const float c1 = ss * LOG2E;
  const float scale_p = 1.0f / 127.0f;
  const size_t vbase = ((size_t)(b * NKV + hk)) * HD * SEQ;

  bf16x8 qf[4];
  {
    const unsigned short* qp =
        qb + ((size_t)(b * SEQ + q0 + wave * 16 + l16) * NH + h) * HD + quad * 8;
#pragma unroll
    for (int s = 0; s < 4; s++) qf[s] = *(const bf16x8*)(qp + s * 32);
  }
  const int qrow = q0 + wave * 16 + l16;      // swapped: thread-local q-row
  const int qrb = q0 + wave * 16 + quad * 4;  // epilogue rows

  // ---- Pass A: l sums ----
  float l = 0.f;
  bf16x8 kreg[4];
  ldK(kreg, kb, b, hk, 0, tid);
  for (int t = 0; t < nt; t++) {
    const int j0 = t * TK;
    __syncthreads();
    stK(Ks, kreg, tid);
    if (t + 1 < nt) ldK(kreg, kb, b, hk, (t + 1) * TK, tid);
    __syncthreads();
    f32x4 sfr[4];
    qk41(sfr, Ks, qf, l16, quad);
    lacc(l, sfr, c1, t == nt - 1, j0, qrow, quad);
  }
  l += __shfl_xor(l, 16);
  l += __shfl_xor(l, 32);
  const float l2il = __log2f(127.0f / fmaxf(l, 1e-30f));

  // ---- Pass B: recompute S, quantize P, PV ----
  f32x4 of[8];
#pragma unroll
  for (int n = 0; n < 8; n++) of[n] = (f32x4){0.f, 0.f, 0.f, 0.f};
  bf16x8 vreg[4];
  ldK(kreg, kb, b, hk, 0, tid);
  ldV(vreg, vbt, vbase, 0, tid);
  for (int t = 0; t < nt; t++) {
    const int j0 = t * TK;
    __syncthreads();
    stK(Ks, kreg, tid);
    stV(Vt, vreg, tid);
    if (t + 1 < nt) {
      ldK(kreg, kb, b, hk, (t + 1) * TK, tid);
      ldV(vreg, vbt, vbase, (t + 1) * TK, tid);
    }
    __syncthreads();
    f32x4 sfr[4];
    qk41(sfr, Ks, qf, l16, quad);
    pquant(Ps, sfr, l2il, c1, t == nt - 1, j0, qrow, wave, l16, quad);
    pvacc1(of, Ps, Vt, wave, l16, quad);  // Ps rows are wave-private; in-wave LDS order
  }

  // ---- epilogue ----
  const float oscale = scale_p * s_v;
  float amax = 0.0f;
#pragma unroll
  for (int n = 0; n < 8; n++)
#pragma unroll
    for (int r = 0; r < 4; r++) {
      float v = of[n][r] * oscale;
      ob[((size_t)(b * SEQ + qrb + r) * NH + h) * HD + n * 16 + l16] = v;
      amax = fmaxf(amax, fabsf(v));
    }
  // amax reduction reusing Ps as scratch (keeps LDS at 45KB for 3 blocks/CU)
  __syncthreads();
  float* red = (float*)Ps;
  red[tid] = amax;
  __syncthreads();
  for (int o = 128; o > 0; o >>= 1) {
    if (tid < o) red[tid] = fmaxf(red[tid], red[tid + o]);
    __syncthreads();
  }
  if (tid == 0) atomicMax(slots + 8, __float_as_uint(red[0]));
}

extern "C" void kernel_launch(void* const* d_in, const int* in_sizes, int n_in,
                              void* d_out, int out_size, void* d_ws, size_t ws_size,
                              hipStream_t stream) {
  const float* hs = (const float*)d_in[0];
  const float* wq = (const float*)d_in[3];
  const float* wk = (const float*)d_in[4];
  const float* wv = (const float*)d_in[5];
  const float* wo = (const float*)d_in[6];
  float* out = (float*)d_out;

  unsigned int* slots = (unsigned int*)d_ws;
  char* p = (char*)d_ws + 256;
  unsigned short* hsq = (unsigned short*)p;  p += 2 * N_HS;  // dead after QKV GEMM
  unsigned short* wqq = (unsigned short*)p;  p += 2 * N_WQ;
  unsigned short* wkq = (unsigned short*)p;  p += 2 * N_WKV;
  unsigned short* wvq = (unsigned short*)p;  p += 2 * N_WKV;
  unsigned short* woq = (unsigned short*)p;  p += 2 * N_WO;
  float* kbuf = (float*)p;                   p += 4 * N_KV;
  float* vbuf = (float*)p;                   p += 4 * N_KV;
  unsigned short* qbf = (unsigned short*)p;  p += 2 * N_Q;
  unsigned short* kbf = (unsigned short*)p;  p += 2 * N_KV;
  unsigned short* vbt = (unsigned short*)p;  p += 2 * N_KV;  // transposed quantized V
  float2* rtab = (float2*)p;                 // RoPE cos/sin table, 1MB
  unsigned short* aobf = hsq;  // alias: hsq dead after QKV GEMM
  float* qbuf = out;           // fp32 q-proj output lives in d_out
  float* aobuf = out;          // fp32 attn output lives in d_out

  hipMemsetAsync(d_ws, 0, 256, stream);

  // slots: 0=x 1=wq 2=wk 3=wv 4=wo 5=q 6=k 7=v 8=ao
  absmax5_k<<<dim3(256, 6), 256, 0, stream>>>(hs, wq, wk, wv, wo, rtab, slots);
  quant5_k<<<dim3(256, 5), 256, 0, stream>>>(hs, wq, wk, wv, wo, slots, hsq, wqq, wkq, wvq, woq);

  const int M = BATCH * SEQ;
  gemm_qkv_k<<<dim3(24, M / 128), 256, 0, stream>>>(hsq, wqq, wkq, wvq, qbuf, kbuf, vbuf, slots);

  rope_kernel<<<1024, 256, 0, stream>>>(qbuf, NH, 4, rtab, slots + 5);
  rope_kernel<<<256, 256, 0, stream>>>(kbuf, NKV, 2, rtab, slots + 6);

  quant2_k<<<dim3(256, 2), 256, 0, stream>>>(qbuf, kbuf, slots, qbf, kbf);
  vtq_k<<<dim3(SEQ / 64, NKV, BATCH), 256, 0, stream>>>(vbuf, slots, vbt);

  attn_mfma_kernel<<<dim3(1024, 1, 1), 256, 0, stream>>>(qbf, kbf, vbt, aobuf, slots);

  quant1_k<<<256, 256, 0, stream>>>(aobuf, N_Q / 4, slots + 8, aobf);

  gemm_o_k<<<dim3(HID / 128, M / 128), 256, 0, stream>>>(aobf, woq, out, slots);
}